// Round 4
// baseline (399.667 us; speedup 1.0000x reference)
//
#include <hip/hip_runtime.h>
#include <hip/hip_bf16.h>
#include <math.h>
#include <float.h>

#define B_Q   1024
#define N_M   50000
#define DIM   256
#define ATOMS 200
#define KSEL  8
#define NCHUNK 40
#define CHUNK  1250       // N_M / NCHUNK exactly
#define MT    128
#define NMT   10          // CHUNK/MT rounded up
#define CPC   8           // candidates kept per (query, chunk)
#define NC    (NCHUNK * CPC)   // 320 candidates per query
#define T16   16          // finalize rescore set
#define TROWS 64          // transform rows per block
#define APX   264         // A-plane LDS row stride in bf16 elems (528B, 16B-aligned)

typedef __attribute__((ext_vector_type(8))) short bf16x8;
typedef __attribute__((ext_vector_type(4))) float f32x4;

static __device__ inline unsigned short f2bf(float f) {
  __hip_bfloat16 h = __float2bfloat16(f);   // RNE
  return *reinterpret_cast<unsigned short*>(&h);
}

// RNE 3-way split (one-time W prep): x ~= s1+s2+s3, residual <= 2^-27 |x|
static __device__ inline void split3(float x, unsigned short& s1,
                                     unsigned short& s2, unsigned short& s3) {
  __hip_bfloat16 b1 = __float2bfloat16(x);
  float f1 = __bfloat162float(b1);
  float r1 = x - f1;
  __hip_bfloat16 b2 = __float2bfloat16(r1);
  float f2 = __bfloat162float(b2);
  __hip_bfloat16 b3 = __float2bfloat16(r1 - f2);
  s1 = *reinterpret_cast<unsigned short*>(&b1);
  s2 = *reinterpret_cast<unsigned short*>(&b2);
  s3 = *reinterpret_cast<unsigned short*>(&b3);
}

// Truncation 3-way split (hot path, 2 VALU/tier): residual <= 2^-24 |x|.
// x - trunc16(x) is exact (Sterbenz). Combined with RNE W tiers, dropped
// cross terms ~1e-7 rel — under the 5e-7 z-error budget.
static __device__ inline void split3t(float x, unsigned short& s1,
                                      unsigned short& s2, unsigned short& s3) {
  const unsigned u = __float_as_uint(x);
  s1 = (unsigned short)(u >> 16);
  const float f1 = __uint_as_float(u & 0xffff0000u);
  const float r1 = x - f1;                       // exact
  const unsigned v = __float_as_uint(r1);
  s2 = (unsigned short)(v >> 16);
  const float f2 = __uint_as_float(v & 0xffff0000u);
  const float r2 = r1 - f2;                      // exact
  s3 = (unsigned short)(__float_as_uint(r2) >> 16);
}

// fp32 tanh via HW v_exp_f32 (~1ulp): rel err ~1.5e-7.
static __device__ inline float tanh32(float z) {
  float tz = fabsf(z) * 2.885390082f;           // 2|z|*log2(e)
  tz = fminf(tz, 120.f);
  const float E = __builtin_amdgcn_exp2f(tz);   // e^{2|z|}
  const float T = 1.f - 2.f / (E + 1.f);
  return (z >= 0.f) ? T : -T;
}

// ---------------------------------------------------------------------------
// W pre-split: Wt planes [n][k] (transposed) as bf16 triple. 256x256, tiny.
// ---------------------------------------------------------------------------
__global__ __launch_bounds__(256) void wsplit_kernel(
    const float* __restrict__ W,
    unsigned short* __restrict__ Wt1, unsigned short* __restrict__ Wt2,
    unsigned short* __restrict__ Wt3)
{
  const int n = blockIdx.x;
  const int k = threadIdx.x;
  unsigned short s1, s2, s3;
  split3(W[(size_t)k * DIM + n], s1, s2, s3);
  Wt1[(size_t)n * DIM + k] = s1;
  Wt2[(size_t)n * DIM + k] = s2;
  Wt3[(size_t)n * DIM + k] = s3;
}

// ---------------------------------------------------------------------------
// Transform: H = to_poincare(X @ W + b); X@W via bf16 MFMA, 3-way Dekker
// split (6 product orders) chained into one fp32 accumulator per m-subtile.
// Block = 64 rows x 1024 threads (16 waves); wave w owns output cols
// [16w,16w+16): Wt is read ONCE per block (24 b128 loads/wave, explicit
// ks+1 double-buffer), A-planes staged in LDS (101KB, truncation splits,
// b128 writes). Per ks: 3 B-loads + 12 A ds_reads + 24 MFMA.
// MFMA layouts (HW-verified here through 4 passing rounds):
// A[m=lane&15][k=quad*8+j], B[n=lane&15][k=quad*8+j], D col=lane&15
// row=quad*4+reg. Epilogue fp32: tanh, 2-level row-norm reduce, scale, aux.
// ---------------------------------------------------------------------------
__global__ __launch_bounds__(1024) void transform_kernel(
    const float* __restrict__ X, int nrows,
    const unsigned short* __restrict__ Wt1, const unsigned short* __restrict__ Wt2,
    const unsigned short* __restrict__ Wt3, const float* __restrict__ bvec,
    float* __restrict__ H, unsigned short* __restrict__ Hb,
    float2* __restrict__ aux)
{
  __shared__ __align__(16) unsigned short X1s[TROWS * APX];
  __shared__ __align__(16) unsigned short X2s[TROWS * APX];
  __shared__ __align__(16) unsigned short X3s[TROWS * APX];
  __shared__ float red[16][TROWS];
  __shared__ float sArr[TROWS];

  const int t    = threadIdx.x;
  const int lane = t & 63;
  const int wave = t >> 6;
  const int row0 = blockIdx.x * TROWS;

  // stage + split X tile [64][256]: thread owns (row r, 16 cols at c0)
  {
    const int r  = t >> 4;
    const int c0 = (t & 15) * 16;
    int gr = row0 + r; if (gr >= nrows) gr = nrows - 1;   // clamp (stores guarded)
    const float4* src = (const float4*)(X + (size_t)gr * DIM + c0);
    bf16x8 p1[2], p2[2], p3[2];
#pragma unroll
    for (int half = 0; half < 2; ++half) {
#pragma unroll
      for (int v = 0; v < 2; ++v) {
        const float4 x4 = src[half * 2 + v];
        const float xv[4] = {x4.x, x4.y, x4.z, x4.w};
#pragma unroll
        for (int i = 0; i < 4; ++i) {
          unsigned short s1, s2, s3;
          split3t(xv[i], s1, s2, s3);
          p1[half][v * 4 + i] = (short)s1;
          p2[half][v * 4 + i] = (short)s2;
          p3[half][v * 4 + i] = (short)s3;
        }
      }
      *(bf16x8*)(X1s + r * APX + c0 + half * 8) = p1[half];
      *(bf16x8*)(X2s + r * APX + c0 + half * 8) = p2[half];
      *(bf16x8*)(X3s + r * APX + c0 + half * 8) = p3[half];
    }
  }
  __syncthreads();

  const int lx   = lane & 15;    // A row m / B col n / D col
  const int quad = lane >> 4;    // k-group / D row-quad
  const int n0   = wave * 16;    // this wave's output col-tile

  f32x4 acc[4];
#pragma unroll
  for (int ms = 0; ms < 4; ++ms) { acc[ms][0] = 0.f; acc[ms][1] = 0.f; acc[ms][2] = 0.f; acc[ms][3] = 0.f; }

  const size_t brow = (size_t)(n0 + lx) * DIM + quad * 8;
  bf16x8 b1c = *(const bf16x8*)(Wt1 + brow);
  bf16x8 b2c = *(const bf16x8*)(Wt2 + brow);
  bf16x8 b3c = *(const bf16x8*)(Wt3 + brow);

#pragma unroll
  for (int ks = 0; ks < 8; ++ks) {
    bf16x8 b1n, b2n, b3n;
    if (ks < 7) {                       // prefetch next k-step's B
      const size_t nb = brow + (ks + 1) * 32;
      b1n = *(const bf16x8*)(Wt1 + nb);
      b2n = *(const bf16x8*)(Wt2 + nb);
      b3n = *(const bf16x8*)(Wt3 + nb);
    }
    const int ko = ks * 32 + quad * 8;
#pragma unroll
    for (int ms = 0; ms < 4; ++ms) {
      const int ar = (ms * 16 + lx) * APX + ko;
      const bf16x8 a1 = *(const bf16x8*)(X1s + ar);
      const bf16x8 a2 = *(const bf16x8*)(X2s + ar);
      const bf16x8 a3 = *(const bf16x8*)(X3s + ar);
      acc[ms] = __builtin_amdgcn_mfma_f32_16x16x32_bf16(a1, b1c, acc[ms], 0, 0, 0);
      acc[ms] = __builtin_amdgcn_mfma_f32_16x16x32_bf16(a1, b2c, acc[ms], 0, 0, 0);
      acc[ms] = __builtin_amdgcn_mfma_f32_16x16x32_bf16(a2, b1c, acc[ms], 0, 0, 0);
      acc[ms] = __builtin_amdgcn_mfma_f32_16x16x32_bf16(a1, b3c, acc[ms], 0, 0, 0);
      acc[ms] = __builtin_amdgcn_mfma_f32_16x16x32_bf16(a2, b2c, acc[ms], 0, 0, 0);
      acc[ms] = __builtin_amdgcn_mfma_f32_16x16x32_bf16(a3, b1c, acc[ms], 0, 0, 0);
    }
    b1c = b1n; b2c = b2n; b3c = b3n;
  }

  // bias + tanh: lane holds rows ms*16+quad*4+r, col n0+lx (bias col-constant)
  const float bb = bvec[n0 + lx];
  float h[4][4];
#pragma unroll
  for (int ms = 0; ms < 4; ++ms)
#pragma unroll
    for (int r = 0; r < 4; ++r)
      h[ms][r] = tanh32(acc[ms][r] + bb);

  // row-norm partial over this wave's 16 cols (shuffle over lx)
  float p[4][4];
#pragma unroll
  for (int ms = 0; ms < 4; ++ms)
#pragma unroll
    for (int r = 0; r < 4; ++r) p[ms][r] = h[ms][r] * h[ms][r];
#pragma unroll
  for (int off = 1; off < 16; off <<= 1)
#pragma unroll
    for (int ms = 0; ms < 4; ++ms)
#pragma unroll
      for (int r = 0; r < 4; ++r) p[ms][r] += __shfl_xor(p[ms][r], off);
  if (lx == 0)
#pragma unroll
    for (int ms = 0; ms < 4; ++ms)
#pragma unroll
      for (int r = 0; r < 4; ++r) red[wave][ms * 16 + quad * 4 + r] = p[ms][r];
  __syncthreads();

  if (t < TROWS) {
    float nsq = 0.f;
#pragma unroll
    for (int w = 0; w < 16; ++w) nsq += red[w][t];
    const float nrm = sqrtf(nsq);
    sArr[t] = (nrm > 0.95f) ? (0.95f / nrm) : 1.f;
  }
  __syncthreads();

  float u[4][4];
#pragma unroll
  for (int ms = 0; ms < 4; ++ms)
#pragma unroll
    for (int r = 0; r < 4; ++r) {
      const float sc = sArr[ms * 16 + quad * 4 + r];
      u[ms][r] = h[ms][r] * sc;
      p[ms][r] = u[ms][r] * u[ms][r];
    }
#pragma unroll
  for (int off = 1; off < 16; off <<= 1)
#pragma unroll
    for (int ms = 0; ms < 4; ++ms)
#pragma unroll
      for (int r = 0; r < 4; ++r) p[ms][r] += __shfl_xor(p[ms][r], off);
  if (lx == 0)
#pragma unroll
    for (int ms = 0; ms < 4; ++ms)
#pragma unroll
      for (int r = 0; r < 4; ++r) red[wave][ms * 16 + quad * 4 + r] = p[ms][r];

  // stores: H fp32 + Hb bf16 (guarded rows)
#pragma unroll
  for (int ms = 0; ms < 4; ++ms)
#pragma unroll
    for (int r = 0; r < 4; ++r) {
      const int grow = row0 + ms * 16 + quad * 4 + r;
      if (grow < nrows) {
        H[(size_t)grow * DIM + n0 + lx]  = u[ms][r];
        Hb[(size_t)grow * DIM + n0 + lx] = f2bf(u[ms][r]);
      }
    }
  __syncthreads();
  if (t < TROWS) {
    const int grow = row0 + t;
    if (grow < nrows) {
      float ysq = 0.f;
#pragma unroll
      for (int w = 0; w < 16; ++w) ysq += red[w][t];
      aux[grow] = make_float2(ysq, 1.f / (1.f - ysq));
    }
  }
}

// ---------------------------------------------------------------------------
// Score (MFMA), v4b: barrier-free + scalarized (v3) + HALF-TILE SOFTWARE
// PIPELINE. (v4 failed to compile: macro comma-splicing; v4b uses two
// explicit SCORE16 macros.) Round-2 post-mortem: v3 removed round-0's
// implicit prefetch (loads in flight across the scan under raw barriers),
// exposing ~300-400cy L2 latency serially per mtile -> 153 us, all pipes
// <31% busy. v4 restores a deeper pipeline with STATIC names (no arrays):
//   X frags = k-half 0 (ks0..3), Y frags = k-half 1 (ks4..7).
//   preload X(0); for mt in 0..8: issue Y(mt) -> MFMA(X) -> advance ptrs,
//   issue X(mt+1) -> MFMA(Y) -> 16 inserts (X(mt+1) flying behind);
//   peeled masked tail mt=9. Loop body branch-free; in-order vmcnt means
//   waiting on X leaves Y + next-X in flight.
// Block/merge structure unchanged from v3 (see its comment for the top-3
// safety argument, E[loss] ~ 2e-5 overall).
// ---------------------------------------------------------------------------
__global__ __launch_bounds__(256) void score_kernel(
    const unsigned short* __restrict__ Hqb, const unsigned short* __restrict__ Hmb,
    const float2* __restrict__ auxq, const float2* __restrict__ auxm,
    float* __restrict__ cand_s, int* __restrict__ cand_i)
{
  __shared__ __align__(16) unsigned short Afs[16 * 64 * 8]; // 16 KB, frag-order
  __shared__ unsigned long long wtop[4][32][CPC];           // 8 KB

  const int t    = threadIdx.x;
  const int lane = t & 63;
  const int wave = t >> 6;
  const int q0   = blockIdx.y * 32;
  const int c    = blockIdx.x;
  const int mbase = c * CHUNK;
  const int lx   = lane & 15;
  const int quad = lane >> 4;

  // stage A fragments into LDS (slot = ks*2+qs; each wave stages 4 slots)
#pragma unroll
  for (int i = 0; i < 4; ++i) {
    const int sl = wave * 4 + i;
    const int ks = sl >> 1, qs = sl & 1;
    const bf16x8 a = *(const bf16x8*)(Hqb + (size_t)(q0 + qs * 16 + lx) * DIM + ks * 32 + quad * 8);
    *(bf16x8*)(Afs + ((size_t)sl * 64 + lane) * 8) = a;
  }
  // per-row query norms (row = qs*4+r; rows 0-3 -> qs=0, rows 4-7 -> qs=1)
  const float xq0 = auxq[q0 +      quad * 4 + 0].x;
  const float xq1 = auxq[q0 +      quad * 4 + 1].x;
  const float xq2 = auxq[q0 +      quad * 4 + 2].x;
  const float xq3 = auxq[q0 +      quad * 4 + 3].x;
  const float xq4 = auxq[q0 + 16 + quad * 4 + 0].x;
  const float xq5 = auxq[q0 + 16 + quad * 4 + 1].x;
  const float xq6 = auxq[q0 + 16 + quad * 4 + 2].x;
  const float xq7 = auxq[q0 + 16 + quad * 4 + 3].x;
  __syncthreads();          // the ONLY pre-merge barrier

  // 24 named packed top-3 regs (sorted ascending: a <= b <= c)
  unsigned long long t0a=~0ULL,t0b=~0ULL,t0c=~0ULL, t1a=~0ULL,t1b=~0ULL,t1c=~0ULL;
  unsigned long long t2a=~0ULL,t2b=~0ULL,t2c=~0ULL, t3a=~0ULL,t3b=~0ULL,t3c=~0ULL;
  unsigned long long t4a=~0ULL,t4b=~0ULL,t4c=~0ULL, t5a=~0ULL,t5b=~0ULL,t5c=~0ULL;
  unsigned long long t6a=~0ULL,t6b=~0ULL,t6c=~0ULL, t7a=~0ULL,t7b=~0ULL,t7c=~0ULL;

  const int colw = wave * 32 + lx;       // within-128-tile column, ms=0
  int midx = mbase + colw;               // global m index (ms=0), += MT per mtile

  // running B pointers (B0 = ms0 row, B1 = ms1 row); +MT*DIM per mtile
  const unsigned short* B0p = Hmb + (size_t)midx * DIM + quad * 8;
  const unsigned short* B1p = B0p + (size_t)16 * DIM;

// one MFMA k-step: A slots (KS*2+0 / KS*2+1) x named B frags
#define KSTEP(KS, BA, BB) do {                                                        \
    const bf16x8 a0_ = *(const bf16x8*)(Afs + (((KS) * 2 + 0) * 64 + lane) * 8);      \
    const bf16x8 a1_ = *(const bf16x8*)(Afs + (((KS) * 2 + 1) * 64 + lane) * 8);      \
    acc00 = __builtin_amdgcn_mfma_f32_16x16x32_bf16(a0_, BA, acc00, 0, 0, 0);         \
    acc01 = __builtin_amdgcn_mfma_f32_16x16x32_bf16(a0_, BB, acc01, 0, 0, 0);         \
    acc10 = __builtin_amdgcn_mfma_f32_16x16x32_bf16(a1_, BA, acc10, 0, 0, 0);         \
    acc11 = __builtin_amdgcn_mfma_f32_16x16x32_bf16(a1_, BB, acc11, 0, 0, 0);         \
  } while (0)

// score + sorted top-3 insert, unconditional (all tokens named vars)
#define SCOREU(ACC, R, YM, RO, GI, XQ, T0, T1, T2) do {                               \
    const float sv_ = fmaxf(fmaf(-2.f, (ACC)[R], (XQ) + (YM)), 0.f) * (RO);           \
    const unsigned long long pk_ =                                                     \
      (((unsigned long long)__float_as_uint(sv_)) << 32) | (unsigned int)(GI);         \
    if (pk_ < T2) {                                                                    \
      T2 = pk_;                                                                        \
      if (T2 < T1) { const unsigned long long x_ = T1; T1 = T2; T2 = x_; }             \
      if (T1 < T0) { const unsigned long long x_ = T0; T0 = T1; T1 = x_; }             \
    }                                                                                  \
  } while (0)

// masked variant (chunk tail only)
#define SCOREM(ACC, R, YM, RO, OK, GI, XQ, T0, T1, T2) do {                           \
    const float sv_ = fmaxf(fmaf(-2.f, (ACC)[R], (XQ) + (YM)), 0.f) * (RO);           \
    const unsigned long long pk_ =                                                     \
      (((unsigned long long)__float_as_uint(sv_)) << 32) | (unsigned int)(GI);         \
    if ((OK) && pk_ < T2) {                                                            \
      T2 = pk_;                                                                        \
      if (T2 < T1) { const unsigned long long x_ = T1; T1 = T2; T2 = x_; }             \
      if (T1 < T0) { const unsigned long long x_ = T0; T0 = T1; T1 = x_; }             \
    }                                                                                  \
  } while (0)

// all 16 scores of one mtile, unmasked (hot loop)
#define SCORE16U do {                                                                 \
    const float ym0 = aux0.x, ro0 = aux0.y;                                           \
    const float ym1 = aux1.x, ro1 = aux1.y;                                           \
    const int   gi0 = midx;                                                           \
    const int   gi1 = midx + 16;                                                      \
    SCOREU(acc00, 0, ym0, ro0, gi0, xq0, t0a, t0b, t0c);                              \
    SCOREU(acc00, 1, ym0, ro0, gi0, xq1, t1a, t1b, t1c);                              \
    SCOREU(acc00, 2, ym0, ro0, gi0, xq2, t2a, t2b, t2c);                              \
    SCOREU(acc00, 3, ym0, ro0, gi0, xq3, t3a, t3b, t3c);                              \
    SCOREU(acc01, 0, ym1, ro1, gi1, xq0, t0a, t0b, t0c);                              \
    SCOREU(acc01, 1, ym1, ro1, gi1, xq1, t1a, t1b, t1c);                              \
    SCOREU(acc01, 2, ym1, ro1, gi1, xq2, t2a, t2b, t2c);                              \
    SCOREU(acc01, 3, ym1, ro1, gi1, xq3, t3a, t3b, t3c);                              \
    SCOREU(acc10, 0, ym0, ro0, gi0, xq4, t4a, t4b, t4c);                              \
    SCOREU(acc10, 1, ym0, ro0, gi0, xq5, t5a, t5b, t5c);                              \
    SCOREU(acc10, 2, ym0, ro0, gi0, xq6, t6a, t6b, t6c);                              \
    SCOREU(acc10, 3, ym0, ro0, gi0, xq7, t7a, t7b, t7c);                              \
    SCOREU(acc11, 0, ym1, ro1, gi1, xq4, t4a, t4b, t4c);                              \
    SCOREU(acc11, 1, ym1, ro1, gi1, xq5, t5a, t5b, t5c);                              \
    SCOREU(acc11, 2, ym1, ro1, gi1, xq6, t6a, t6b, t6c);                              \
    SCOREU(acc11, 3, ym1, ro1, gi1, xq7, t7a, t7b, t7c);                              \
  } while (0)

// all 16 scores of one mtile, masked (tail)
#define SCORE16M(OK0, OK1) do {                                                       \
    const float ym0 = aux0.x, ro0 = aux0.y;                                           \
    const float ym1 = aux1.x, ro1 = aux1.y;                                           \
    const int   gi0 = midx;                                                           \
    const int   gi1 = midx + 16;                                                      \
    SCOREM(acc00, 0, ym0, ro0, OK0, gi0, xq0, t0a, t0b, t0c);                         \
    SCOREM(acc00, 1, ym0, ro0, OK0, gi0, xq1, t1a, t1b, t1c);                         \
    SCOREM(acc00, 2, ym0, ro0, OK0, gi0, xq2, t2a, t2b, t2c);                         \
    SCOREM(acc00, 3, ym0, ro0, OK0, gi0, xq3, t3a, t3b, t3c);                         \
    SCOREM(acc01, 0, ym1, ro1, OK1, gi1, xq0, t0a, t0b, t0c);                         \
    SCOREM(acc01, 1, ym1, ro1, OK1, gi1, xq1, t1a, t1b, t1c);                         \
    SCOREM(acc01, 2, ym1, ro1, OK1, gi1, xq2, t2a, t2b, t2c);                         \
    SCOREM(acc01, 3, ym1, ro1, OK1, gi1, xq3, t3a, t3b, t3c);                         \
    SCOREM(acc10, 0, ym0, ro0, OK0, gi0, xq4, t4a, t4b, t4c);                         \
    SCOREM(acc10, 1, ym0, ro0, OK0, gi0, xq5, t5a, t5b, t5c);                         \
    SCOREM(acc10, 2, ym0, ro0, OK0, gi0, xq6, t6a, t6b, t6c);                         \
    SCOREM(acc10, 3, ym0, ro0, OK0, gi0, xq7, t7a, t7b, t7c);                         \
    SCOREM(acc11, 0, ym1, ro1, OK1, gi1, xq4, t4a, t4b, t4c);                         \
    SCOREM(acc11, 1, ym1, ro1, OK1, gi1, xq5, t5a, t5b, t5c);                         \
    SCOREM(acc11, 2, ym1, ro1, OK1, gi1, xq6, t6a, t6b, t6c);                         \
    SCOREM(acc11, 3, ym1, ro1, OK1, gi1, xq7, t7a, t7b, t7c);                         \
  } while (0)

  // preload X = k-half0 of mtile 0
  bf16x8 xA0 = *(const bf16x8*)(B0p + 0);
  bf16x8 xA1 = *(const bf16x8*)(B0p + 32);
  bf16x8 xA2 = *(const bf16x8*)(B0p + 64);
  bf16x8 xA3 = *(const bf16x8*)(B0p + 96);
  bf16x8 xB0 = *(const bf16x8*)(B1p + 0);
  bf16x8 xB1 = *(const bf16x8*)(B1p + 32);
  bf16x8 xB2 = *(const bf16x8*)(B1p + 64);
  bf16x8 xB3 = *(const bf16x8*)(B1p + 96);

  for (int mt = 0; mt < NMT - 1; ++mt) {      // mt 0..8: branch-free body
    // issue Y = k-half1 of current mtile (+ aux for the score phase)
    bf16x8 yA0 = *(const bf16x8*)(B0p + 128);
    bf16x8 yA1 = *(const bf16x8*)(B0p + 160);
    bf16x8 yA2 = *(const bf16x8*)(B0p + 192);
    bf16x8 yA3 = *(const bf16x8*)(B0p + 224);
    bf16x8 yB0 = *(const bf16x8*)(B1p + 128);
    bf16x8 yB1 = *(const bf16x8*)(B1p + 160);
    bf16x8 yB2 = *(const bf16x8*)(B1p + 192);
    bf16x8 yB3 = *(const bf16x8*)(B1p + 224);
    const float2 aux0 = auxm[midx];
    const float2 aux1 = auxm[midx + 16];

    f32x4 acc00 = {0.f, 0.f, 0.f, 0.f};
    f32x4 acc01 = {0.f, 0.f, 0.f, 0.f};
    f32x4 acc10 = {0.f, 0.f, 0.f, 0.f};
    f32x4 acc11 = {0.f, 0.f, 0.f, 0.f};

    // compute on X (waits only X's loads; Y stays in flight)
    KSTEP(0, xA0, xB0);
    KSTEP(1, xA1, xB1);
    KSTEP(2, xA2, xB2);
    KSTEP(3, xA3, xB3);

    // advance, issue X = k-half0 of NEXT mtile (in flight across inserts)
    B0p += (size_t)MT * DIM;
    B1p += (size_t)MT * DIM;
    xA0 = *(const bf16x8*)(B0p + 0);
    xA1 = *(const bf16x8*)(B0p + 32);
    xA2 = *(const bf16x8*)(B0p + 64);
    xA3 = *(const bf16x8*)(B0p + 96);
    xB0 = *(const bf16x8*)(B1p + 0);
    xB1 = *(const bf16x8*)(B1p + 32);
    xB2 = *(const bf16x8*)(B1p + 64);
    xB3 = *(const bf16x8*)(B1p + 96);

    // compute on Y
    KSTEP(4, yA0, yB0);
    KSTEP(5, yA1, yB1);
    KSTEP(6, yA2, yB2);
    KSTEP(7, yA3, yB3);

    // scores -> per-lane top-3 (unmasked; rem >= 128 for mt <= 8)
    SCORE16U;
    midx += MT;
  }

  { // peeled tail mtile mt = 9: rem = CHUNK - 9*MT (= 98), masked, no prefetch
    const int rem = CHUNK - (NMT - 1) * MT;
    const bool ok0 = colw < rem;
    const bool ok1 = colw + 16 < rem;
    bf16x8 yA0 = *(const bf16x8*)(B0p + 128);
    bf16x8 yA1 = *(const bf16x8*)(B0p + 160);
    bf16x8 yA2 = *(const bf16x8*)(B0p + 192);
    bf16x8 yA3 = *(const bf16x8*)(B0p + 224);
    bf16x8 yB0 = *(const bf16x8*)(B1p + 128);
    bf16x8 yB1 = *(const bf16x8*)(B1p + 160);
    bf16x8 yB2 = *(const bf16x8*)(B1p + 192);
    bf16x8 yB3 = *(const bf16x8*)(B1p + 224);
    const float2 aux0 = auxm[midx];
    const float2 aux1 = auxm[midx + 16];

    f32x4 acc00 = {0.f, 0.f, 0.f, 0.f};
    f32x4 acc01 = {0.f, 0.f, 0.f, 0.f};
    f32x4 acc10 = {0.f, 0.f, 0.f, 0.f};
    f32x4 acc11 = {0.f, 0.f, 0.f, 0.f};

    KSTEP(0, xA0, xB0);
    KSTEP(1, xA1, xB1);
    KSTEP(2, xA2, xB2);
    KSTEP(3, xA3, xB3);
    KSTEP(4, yA0, yB0);
    KSTEP(5, yA1, yB1);
    KSTEP(6, yA2, yB2);
    KSTEP(7, yA3, yB3);

    SCORE16M(ok0, ok1);
  }

#undef KSTEP
#undef SCOREU
#undef SCOREM
#undef SCORE16U
#undef SCORE16M

  // per-wave extraction: per query-row, 16 lanes x top-3 -> wave top-8.
  // (quads handle 4 query-rows in parallel; shfl offsets 1..8 stay in-quad)
#define EXTRACT_ROW(WIDX, T0, T1, T2) do {                                            \
    unsigned long long p0 = T0, p1 = T1, p2 = T2;                                     \
    for (int rd = 0; rd < CPC; ++rd) {                                                \
      unsigned long long lm = (p0 < p1) ? p0 : p1;                                    \
      lm = (p2 < lm) ? p2 : lm;                                                       \
      unsigned long long gm = lm;                                                     \
      for (int off = 1; off < 16; off <<= 1) {                                        \
        const unsigned long long o = __shfl_xor(gm, off);                             \
        gm = (o < gm) ? o : gm;                                                       \
      }                                                                               \
      if      (p0 == gm) p0 = ~0ULL;                                                  \
      else if (p1 == gm) p1 = ~0ULL;                                                  \
      else if (p2 == gm) p2 = ~0ULL;                                                  \
      if (lx == 0) wtop[wave][WIDX][rd] = gm;                                         \
    }                                                                                 \
  } while (0)

  EXTRACT_ROW(quad * 4 + 0,      t0a, t0b, t0c);
  EXTRACT_ROW(quad * 4 + 1,      t1a, t1b, t1c);
  EXTRACT_ROW(quad * 4 + 2,      t2a, t2b, t2c);
  EXTRACT_ROW(quad * 4 + 3,      t3a, t3b, t3c);
  EXTRACT_ROW(16 + quad * 4 + 0, t4a, t4b, t4c);
  EXTRACT_ROW(16 + quad * 4 + 1, t5a, t5b, t5c);
  EXTRACT_ROW(16 + quad * 4 + 2, t6a, t6b, t6c);
  EXTRACT_ROW(16 + quad * 4 + 3, t7a, t7b, t7c);
#undef EXTRACT_ROW
  __syncthreads();

  // cross-wave merge: 8 threads per query, 4 waves x 8 -> top-8 -> cand
  {
    const int qr = t >> 3;        // 0..31
    const int sp = t & 7;
    unsigned long long v0 = wtop[0][qr][sp];
    unsigned long long v1 = wtop[1][qr][sp];
    unsigned long long v2 = wtop[2][qr][sp];
    unsigned long long v3 = wtop[3][qr][sp];
    const size_t cbase = ((size_t)(q0 + qr) * NCHUNK + c) * CPC;
    for (int rd = 0; rd < CPC; ++rd) {
      unsigned long long lm = (v0 < v1) ? v0 : v1;
      const unsigned long long l2 = (v2 < v3) ? v2 : v3;
      lm = (l2 < lm) ? l2 : lm;
      unsigned long long gm = lm;
#pragma unroll
      for (int off = 1; off < 8; off <<= 1) {
        const unsigned long long o = __shfl_xor(gm, off);
        gm = (o < gm) ? o : gm;
      }
      if      (v0 == gm) v0 = ~0ULL;
      else if (v1 == gm) v1 = ~0ULL;
      else if (v2 == gm) v2 = ~0ULL;
      else if (v3 == gm) v3 = ~0ULL;
      if (sp == 0) {
        cand_s[cbase + rd] = __uint_as_float((unsigned int)(gm >> 32));
        cand_i[cbase + rd] = (int)(unsigned int)(gm & 0xffffffffu);
      }
    }
  }
}

// ---------------------------------------------------------------------------
// Finalize: per query, 256 threads (4 waves): parallel candidate merge
// 320 -> 4x16 -> top-16 (fp32 score, idx tie-break), fp64 rescore (4 cands
// per wave) -> exact top-8 order, softmax, parallel mask gather.
// ---------------------------------------------------------------------------
__global__ __launch_bounds__(256) void finalize_kernel(
    const float* __restrict__ Hq, const float* __restrict__ Hm,
    const float* __restrict__ masks,
    const float* __restrict__ cand_s, const int* __restrict__ cand_i,
    float* __restrict__ outW, float* __restrict__ outH)
{
  const int q    = blockIdx.x;
  const int t    = threadIdx.x;
  const int lane = t & 63;
  const int wave = t >> 6;

  __shared__ unsigned long long wtop[4][T16];
  __shared__ int    selIdx[T16];
  __shared__ double dArr[T16];
  __shared__ int    fin_i[KSEL];
  __shared__ double fin_d[KSEL];
  __shared__ double ew[KSEL];

  // phase 1: each wave takes 80 candidates -> its top-16 (indices unique)
  {
    const size_t base = (size_t)q * NC + (size_t)wave * (NC / 4);
    unsigned long long pk[2];
#pragma unroll
    for (int s = 0; s < 2; ++s) {
      const int c = lane + 64 * s;
      pk[s] = (c < NC / 4)
        ? ((((unsigned long long)__float_as_uint(cand_s[base + c])) << 32) | (unsigned int)cand_i[base + c])
        : ~0ULL;
    }
    for (int r = 0; r < T16; ++r) {
      unsigned long long lm = (pk[0] < pk[1]) ? pk[0] : pk[1];
      unsigned long long gm = lm;
#pragma unroll
      for (int off = 1; off < 64; off <<= 1) {
        unsigned long long o = __shfl_xor(gm, off);
        gm = (o < gm) ? o : gm;
      }
      bool done = false;
#pragma unroll
      for (int s = 0; s < 2; ++s) if (!done && pk[s] == gm) { pk[s] = ~0ULL; done = true; }
      if (lane == 0) wtop[wave][r] = gm;
    }
  }
  __syncthreads();

  // phase 2: wave 0 merges 64 -> global top-16
  if (wave == 0) {
    unsigned long long v = wtop[lane >> 4][lane & 15];
    for (int r = 0; r < T16; ++r) {
      unsigned long long gm = v;
#pragma unroll
      for (int off = 1; off < 64; off <<= 1) {
        unsigned long long o = __shfl_xor(gm, off);
        gm = (o < gm) ? o : gm;
      }
      if (v == gm) v = ~0ULL;
      if (lane == 0) selIdx[r] = (int)(unsigned int)(gm & 0xffffffffULL);
    }
  }
  __syncthreads();

  // phase 3: fp64 rescore, 4 candidates per wave
  const float4 q4 = *(const float4*)(Hq + (size_t)q * DIM + 4 * lane);
  double xp_ = (double)q4.x * q4.x + (double)q4.y * q4.y + (double)q4.z * q4.z + (double)q4.w * q4.w;
#pragma unroll
  for (int off = 1; off < 64; off <<= 1) xp_ += __shfl_xor(xp_, off);
  const double xsq = xp_;

  for (int r = wave; r < T16; r += 4) {
    const int cidx = selIdx[r];
    const float4 m4 = *(const float4*)(Hm + (size_t)cidx * DIM + 4 * lane);
    double dp = (double)q4.x * m4.x + (double)q4.y * m4.y + (double)q4.z * m4.z + (double)q4.w * m4.w;
    double yp = (double)m4.x * m4.x + (double)m4.y * m4.y + (double)m4.z * m4.z + (double)m4.w * m4.w;
#pragma unroll
    for (int off = 1; off < 64; off <<= 1) { dp += __shfl_xor(dp, off); yp += __shfl_xor(yp, off); }
    if (lane == 0) {
      double diff = xsq + yp - 2.0 * dp; if (diff < 0.0) diff = 0.0;
      double den = (1.0 - xsq) * (1.0 - yp);
      double arg = 1.0 + 2.0 * diff / (den + 1e-8);
      const double lo = 1.0 + 1e-6;
      if (arg < lo) arg = lo;
      dArr[r] = log(arg + sqrt(arg * arg - 1.0));   // arccosh
    }
  }
  __syncthreads();

  // phase 4: exact rank (dist, idx) -> top-8, softmax
  if (t < T16) {
    const double dj = dArr[t]; const int ij = selIdx[t];
    int rank = 0;
#pragma unroll
    for (int i = 0; i < T16; ++i)
      rank += (dArr[i] < dj || (dArr[i] == dj && selIdx[i] < ij)) ? 1 : 0;
    if (rank < KSEL) { fin_d[rank] = dj; fin_i[rank] = ij; }
  }
  __syncthreads();
  if (t < KSEL) ew[t] = exp(fin_d[0] - fin_d[t]);
  __syncthreads();
  if (t < KSEL) {
    double ssum = 0.0;
#pragma unroll
    for (int i = 0; i < KSEL; ++i) ssum += ew[i];
    outW[(size_t)q * KSEL + t] = (float)(ew[t] / ssum);
  }

  // phase 5: mask gather, 32 threads per output row
  const int g  = t >> 5;
  const int l0 = t & 31;
  const int row = fin_i[g];
  for (int l = l0; l < ATOMS; l += 32)
    outH[((size_t)q * KSEL + g) * ATOMS + l] = masks[(size_t)row * ATOMS + l];
}

// ---------------------------------------------------------------------------
extern "C" void kernel_launch(void* const* d_in, const int* in_sizes, int n_in,
                              void* d_out, int out_size, void* d_ws, size_t ws_size,
                              hipStream_t stream) {
  const float* Q     = (const float*)d_in[0];   // [1024,256]
  const float* M     = (const float*)d_in[1];   // [50000,256]
  const float* masks = (const float*)d_in[2];   // [50000,200]
  const float* W     = (const float*)d_in[3];   // [256,256]
  const float* bv    = (const float*)d_in[4];   // [256]
  // d_in[5] = k (always 8, hard-coded)

  char* w = (char*)d_ws;
  float*          Hq   = (float*)(w);                       //  1,048,576 B
  float*          Hm   = (float*)(w + 1048576);             // 51,200,000 B
  unsigned short* Hqb  = (unsigned short*)(w + 52248576);   //    524,288 B
  unsigned short* Hmb  = (unsigned short*)(w + 52772864);   // 25,624,576 B (padded to 50048 rows)
  float2*         auxq = (float2*)(w + 78397440);           //      8,192 B
  float2*         auxm = (float2*)(w + 78405632);           //    400,384 B (padded)
  float*          cs   = (float*)(w + 78806016);            //  1,310,720 B
  int*            cix  = (int*)(w + 80116736);              //  1,310,720 B -> 81,427,456 total

  // Wt bf16 planes alias the cand_s region (dead until score_kernel writes it)
  unsigned short* Wt1 = (unsigned short*)(w + 78806016);    // 3 x 131,072 B
  unsigned short* Wt2 = Wt1 + DIM * DIM;
  unsigned short* Wt3 = Wt2 + DIM * DIM;

  wsplit_kernel<<<DIM, DIM, 0, stream>>>(W, Wt1, Wt2, Wt3);
  transform_kernel<<<(B_Q + TROWS - 1) / TROWS, 1024, 0, stream>>>(Q, B_Q, Wt1, Wt2, Wt3, bv, Hq, Hqb, auxq);
  transform_kernel<<<(N_M + TROWS - 1) / TROWS, 1024, 0, stream>>>(M, N_M, Wt1, Wt2, Wt3, bv, Hm, Hmb, auxm);
  score_kernel<<<dim3(NCHUNK, B_Q / 32), 256, 0, stream>>>(Hqb, Hmb, auxq, auxm, cs, cix);
  finalize_kernel<<<B_Q, 256, 0, stream>>>(Hq, Hm, masks, cs, cix,
                                           (float*)d_out, (float*)d_out + (size_t)B_Q * KSEL);
}

// Round 6
// 360.031 us; speedup vs baseline: 1.1101x; 1.1101x over previous
//
#include <hip/hip_runtime.h>
#include <hip/hip_bf16.h>
#include <math.h>
#include <float.h>

#define B_Q   1024
#define N_M   50000
#define DIM   256
#define ATOMS 200
#define KSEL  8
#define NCHUNK 40
#define CHUNK  1280       // rows per chunk (16-aligned for fragment groups)
#define MT    128
#define NMT   10          // CHUNK/MT exactly
#define CPC   8           // candidates kept per (query, chunk)
#define NC    (NCHUNK * CPC)   // 320 candidates per query
#define T16   16          // finalize rescore set
#define TROWS 64          // transform rows per block
#define APX   264         // A-plane LDS row stride in bf16 elems (528B, 16B-aligned)

typedef __attribute__((ext_vector_type(8))) short bf16x8;
typedef __attribute__((ext_vector_type(4))) float f32x4;

static __device__ inline unsigned short f2bf(float f) {
  __hip_bfloat16 h = __float2bfloat16(f);   // RNE
  return *reinterpret_cast<unsigned short*>(&h);
}

// RNE 3-way split (one-time W prep): x ~= s1+s2+s3, residual <= 2^-27 |x|
static __device__ inline void split3(float x, unsigned short& s1,
                                     unsigned short& s2, unsigned short& s3) {
  __hip_bfloat16 b1 = __float2bfloat16(x);
  float f1 = __bfloat162float(b1);
  float r1 = x - f1;
  __hip_bfloat16 b2 = __float2bfloat16(r1);
  float f2 = __bfloat162float(b2);
  __hip_bfloat16 b3 = __float2bfloat16(r1 - f2);
  s1 = *reinterpret_cast<unsigned short*>(&b1);
  s2 = *reinterpret_cast<unsigned short*>(&b2);
  s3 = *reinterpret_cast<unsigned short*>(&b3);
}

// Truncation 3-way split (hot path, 2 VALU/tier): residual <= 2^-24 |x|.
static __device__ inline void split3t(float x, unsigned short& s1,
                                      unsigned short& s2, unsigned short& s3) {
  const unsigned u = __float_as_uint(x);
  s1 = (unsigned short)(u >> 16);
  const float f1 = __uint_as_float(u & 0xffff0000u);
  const float r1 = x - f1;                       // exact
  const unsigned v = __float_as_uint(r1);
  s2 = (unsigned short)(v >> 16);
  const float f2 = __uint_as_float(v & 0xffff0000u);
  const float r2 = r1 - f2;                      // exact
  s3 = (unsigned short)(__float_as_uint(r2) >> 16);
}

// fp32 tanh via HW v_exp_f32 (~1ulp): rel err ~1.5e-7.
static __device__ inline float tanh32(float z) {
  float tz = fabsf(z) * 2.885390082f;           // 2|z|*log2(e)
  tz = fminf(tz, 120.f);
  const float E = __builtin_amdgcn_exp2f(tz);   // e^{2|z|}
  const float T = 1.f - 2.f / (E + 1.f);
  return (z >= 0.f) ? T : -T;
}

// ---------------------------------------------------------------------------
// W pre-split: Wt planes [n][k] (transposed) as bf16 triple. 256x256, tiny.
// ---------------------------------------------------------------------------
__global__ __launch_bounds__(256) void wsplit_kernel(
    const float* __restrict__ W,
    unsigned short* __restrict__ Wt1, unsigned short* __restrict__ Wt2,
    unsigned short* __restrict__ Wt3)
{
  const int n = blockIdx.x;
  const int k = threadIdx.x;
  unsigned short s1, s2, s3;
  split3(W[(size_t)k * DIM + n], s1, s2, s3);
  Wt1[(size_t)n * DIM + k] = s1;
  Wt2[(size_t)n * DIM + k] = s2;
  Wt3[(size_t)n * DIM + k] = s3;
}

// ---------------------------------------------------------------------------
// Transform: H = to_poincare(X @ W + b); X@W via bf16 MFMA, 3-way Dekker
// split (6 product orders) chained into one fp32 accumulator per m-subtile.
// v5 change: Hb is written in MFMA B-FRAGMENT-MAJOR layout
//   Frag[g][ks][lane][j]  (elem off = ((g*8+ks)*64 + lane)*8 + j)
//   where g=row>>4, ks=col>>5, lane=((col>>3)&3)*16 + (row&15), j=col&7.
// This makes score_kernel's B/A loads lane-contiguous (1KB per wave-load,
// fully coalesced) instead of 16 scattered 512B-strided rows — round-4 PMC
// showed the scattered pattern saturates the per-CU VMEM path at
// ~8.7 B/cyc/CU (1/6th of the coalesced ceiling).
// ---------------------------------------------------------------------------
__global__ __launch_bounds__(1024) void transform_kernel(
    const float* __restrict__ X, int nrows,
    const unsigned short* __restrict__ Wt1, const unsigned short* __restrict__ Wt2,
    const unsigned short* __restrict__ Wt3, const float* __restrict__ bvec,
    float* __restrict__ H, unsigned short* __restrict__ Hb,
    float2* __restrict__ aux)
{
  __shared__ __align__(16) unsigned short X1s[TROWS * APX];
  __shared__ __align__(16) unsigned short X2s[TROWS * APX];
  __shared__ __align__(16) unsigned short X3s[TROWS * APX];
  __shared__ float red[16][TROWS];
  __shared__ float sArr[TROWS];

  const int t    = threadIdx.x;
  const int lane = t & 63;
  const int wave = t >> 6;
  const int row0 = blockIdx.x * TROWS;

  // stage + split X tile [64][256]: thread owns (row r, 16 cols at c0)
  {
    const int r  = t >> 4;
    const int c0 = (t & 15) * 16;
    int gr = row0 + r; if (gr >= nrows) gr = nrows - 1;   // clamp (stores guarded)
    const float4* src = (const float4*)(X + (size_t)gr * DIM + c0);
    bf16x8 p1[2], p2[2], p3[2];
#pragma unroll
    for (int half = 0; half < 2; ++half) {
#pragma unroll
      for (int v = 0; v < 2; ++v) {
        const float4 x4 = src[half * 2 + v];
        const float xv[4] = {x4.x, x4.y, x4.z, x4.w};
#pragma unroll
        for (int i = 0; i < 4; ++i) {
          unsigned short s1, s2, s3;
          split3t(xv[i], s1, s2, s3);
          p1[half][v * 4 + i] = (short)s1;
          p2[half][v * 4 + i] = (short)s2;
          p3[half][v * 4 + i] = (short)s3;
        }
      }
      *(bf16x8*)(X1s + r * APX + c0 + half * 8) = p1[half];
      *(bf16x8*)(X2s + r * APX + c0 + half * 8) = p2[half];
      *(bf16x8*)(X3s + r * APX + c0 + half * 8) = p3[half];
    }
  }
  __syncthreads();

  const int lx   = lane & 15;    // A row m / B col n / D col
  const int quad = lane >> 4;    // k-group / D row-quad
  const int n0   = wave * 16;    // this wave's output col-tile

  f32x4 acc[4];
#pragma unroll
  for (int ms = 0; ms < 4; ++ms) { acc[ms][0] = 0.f; acc[ms][1] = 0.f; acc[ms][2] = 0.f; acc[ms][3] = 0.f; }

  const size_t brow = (size_t)(n0 + lx) * DIM + quad * 8;
  bf16x8 b1c = *(const bf16x8*)(Wt1 + brow);
  bf16x8 b2c = *(const bf16x8*)(Wt2 + brow);
  bf16x8 b3c = *(const bf16x8*)(Wt3 + brow);

#pragma unroll
  for (int ks = 0; ks < 8; ++ks) {
    bf16x8 b1n, b2n, b3n;
    if (ks < 7) {                       // prefetch next k-step's B
      const size_t nb = brow + (ks + 1) * 32;
      b1n = *(const bf16x8*)(Wt1 + nb);
      b2n = *(const bf16x8*)(Wt2 + nb);
      b3n = *(const bf16x8*)(Wt3 + nb);
    }
    const int ko = ks * 32 + quad * 8;
#pragma unroll
    for (int ms = 0; ms < 4; ++ms) {
      const int ar = (ms * 16 + lx) * APX + ko;
      const bf16x8 a1 = *(const bf16x8*)(X1s + ar);
      const bf16x8 a2 = *(const bf16x8*)(X2s + ar);
      const bf16x8 a3 = *(const bf16x8*)(X3s + ar);
      acc[ms] = __builtin_amdgcn_mfma_f32_16x16x32_bf16(a1, b1c, acc[ms], 0, 0, 0);
      acc[ms] = __builtin_amdgcn_mfma_f32_16x16x32_bf16(a1, b2c, acc[ms], 0, 0, 0);
      acc[ms] = __builtin_amdgcn_mfma_f32_16x16x32_bf16(a2, b1c, acc[ms], 0, 0, 0);
      acc[ms] = __builtin_amdgcn_mfma_f32_16x16x32_bf16(a1, b3c, acc[ms], 0, 0, 0);
      acc[ms] = __builtin_amdgcn_mfma_f32_16x16x32_bf16(a2, b2c, acc[ms], 0, 0, 0);
      acc[ms] = __builtin_amdgcn_mfma_f32_16x16x32_bf16(a3, b1c, acc[ms], 0, 0, 0);
    }
    b1c = b1n; b2c = b2n; b3c = b3n;
  }

  // bias + tanh: lane holds rows ms*16+quad*4+r, col n0+lx (bias col-constant)
  const float bb = bvec[n0 + lx];
  float h[4][4];
#pragma unroll
  for (int ms = 0; ms < 4; ++ms)
#pragma unroll
    for (int r = 0; r < 4; ++r)
      h[ms][r] = tanh32(acc[ms][r] + bb);

  // row-norm partial over this wave's 16 cols (shuffle over lx)
  float p[4][4];
#pragma unroll
  for (int ms = 0; ms < 4; ++ms)
#pragma unroll
    for (int r = 0; r < 4; ++r) p[ms][r] = h[ms][r] * h[ms][r];
#pragma unroll
  for (int off = 1; off < 16; off <<= 1)
#pragma unroll
    for (int ms = 0; ms < 4; ++ms)
#pragma unroll
      for (int r = 0; r < 4; ++r) p[ms][r] += __shfl_xor(p[ms][r], off);
  if (lx == 0)
#pragma unroll
    for (int ms = 0; ms < 4; ++ms)
#pragma unroll
      for (int r = 0; r < 4; ++r) red[wave][ms * 16 + quad * 4 + r] = p[ms][r];
  __syncthreads();

  if (t < TROWS) {
    float nsq = 0.f;
#pragma unroll
    for (int w = 0; w < 16; ++w) nsq += red[w][t];
    const float nrm = sqrtf(nsq);
    sArr[t] = (nrm > 0.95f) ? (0.95f / nrm) : 1.f;
  }
  __syncthreads();

  float u[4][4];
#pragma unroll
  for (int ms = 0; ms < 4; ++ms)
#pragma unroll
    for (int r = 0; r < 4; ++r) {
      const float sc = sArr[ms * 16 + quad * 4 + r];
      u[ms][r] = h[ms][r] * sc;
      p[ms][r] = u[ms][r] * u[ms][r];
    }
#pragma unroll
  for (int off = 1; off < 16; off <<= 1)
#pragma unroll
    for (int ms = 0; ms < 4; ++ms)
#pragma unroll
      for (int r = 0; r < 4; ++r) p[ms][r] += __shfl_xor(p[ms][r], off);
  if (lx == 0)
#pragma unroll
    for (int ms = 0; ms < 4; ++ms)
#pragma unroll
      for (int r = 0; r < 4; ++r) red[wave][ms * 16 + quad * 4 + r] = p[ms][r];

  // stores: H fp32 (row-major) + Hb bf16 (FRAGMENT-MAJOR, guarded rows)
  const int colv = n0 + lx;
  const int ksb  = colv >> 5;                         // fragment k-slot
  const int qoff = ((colv >> 3) & 3) * 128 + (colv & 7);  // quad*16 lanes *8 + j
#pragma unroll
  for (int ms = 0; ms < 4; ++ms)
#pragma unroll
    for (int r = 0; r < 4; ++r) {
      const int grow = row0 + ms * 16 + quad * 4 + r;
      if (grow < nrows) {
        H[(size_t)grow * DIM + colv] = u[ms][r];
        Hb[((size_t)((row0 >> 4) + ms) * 8 + ksb) * 512 + qoff + (quad * 4 + r) * 8]
            = f2bf(u[ms][r]);
      }
    }
  __syncthreads();
  if (t < TROWS) {
    const int grow = row0 + t;
    if (grow < nrows) {
      float ysq = 0.f;
#pragma unroll
      for (int w = 0; w < 16; ++w) ysq += red[w][t];
      aux[grow] = make_float2(ysq, 1.f / (1.f - ysq));
    }
  }
}

// ---------------------------------------------------------------------------
// Score (MFMA), v5: v4b pipeline + FRAGMENT-MAJOR B loads (coalesced).
// Round-4 PMC: all schedule variants stuck at ~8.7 B/cyc/CU — the scattered
// 16-rows-per-quarter-wave B-load pattern serialized in the per-CU TA/L1
// path. Hmb/Hqb are now stored fragment-major (see transform), so every
// B/A global load is one contiguous 1KB wave-access (lane L reads bytes
// [16L,16L+16)). CHUNK=1280 (16-aligned groups): chunks 0..38 = 10 clean
// unmasked mtiles; chunk 39 has 80 valid rows -> one masked mtile (reads
// stay inside the padded 50048-row region; junk cols masked as before).
// Pipeline, per-lane packed-u64 top-3, extraction and merge: as v4b.
// ---------------------------------------------------------------------------
__global__ __launch_bounds__(256) void score_kernel(
    const unsigned short* __restrict__ Hqb, const unsigned short* __restrict__ Hmb,
    const float2* __restrict__ auxq, const float2* __restrict__ auxm,
    float* __restrict__ cand_s, int* __restrict__ cand_i)
{
  __shared__ __align__(16) unsigned short Afs[16 * 64 * 8]; // 16 KB, frag-order
  __shared__ unsigned long long wtop[4][32][CPC];           // 8 KB

  const int t    = threadIdx.x;
  const int lane = t & 63;
  const int wave = t >> 6;
  const int q0   = blockIdx.y * 32;
  const int c    = blockIdx.x;
  const int mbase = c * CHUNK;
  const int lx   = lane & 15;
  const int quad = lane >> 4;

  // stage A fragments into LDS (slot = ks*2+qs; frag-major source, coalesced)
#pragma unroll
  for (int i = 0; i < 4; ++i) {
    const int sl = wave * 4 + i;
    const int ks = sl >> 1, qs = sl & 1;
    const bf16x8 a = *(const bf16x8*)(Hqb + ((size_t)((q0 >> 4) + qs) * 8 + ks) * 512 + (size_t)lane * 8);
    *(bf16x8*)(Afs + ((size_t)sl * 64 + lane) * 8) = a;
  }
  // per-row query norms (row = qs*4+r; rows 0-3 -> qs=0, rows 4-7 -> qs=1)
  const float xq0 = auxq[q0 +      quad * 4 + 0].x;
  const float xq1 = auxq[q0 +      quad * 4 + 1].x;
  const float xq2 = auxq[q0 +      quad * 4 + 2].x;
  const float xq3 = auxq[q0 +      quad * 4 + 3].x;
  const float xq4 = auxq[q0 + 16 + quad * 4 + 0].x;
  const float xq5 = auxq[q0 + 16 + quad * 4 + 1].x;
  const float xq6 = auxq[q0 + 16 + quad * 4 + 2].x;
  const float xq7 = auxq[q0 + 16 + quad * 4 + 3].x;
  __syncthreads();          // the ONLY pre-merge barrier

  // 24 named packed top-3 regs (sorted ascending: a <= b <= c)
  unsigned long long t0a=~0ULL,t0b=~0ULL,t0c=~0ULL, t1a=~0ULL,t1b=~0ULL,t1c=~0ULL;
  unsigned long long t2a=~0ULL,t2b=~0ULL,t2c=~0ULL, t3a=~0ULL,t3b=~0ULL,t3c=~0ULL;
  unsigned long long t4a=~0ULL,t4b=~0ULL,t4c=~0ULL, t5a=~0ULL,t5b=~0ULL,t5c=~0ULL;
  unsigned long long t6a=~0ULL,t6b=~0ULL,t6c=~0ULL, t7a=~0ULL,t7b=~0ULL,t7c=~0ULL;

  const int colw = wave * 32 + lx;       // within-128-tile column, ms=0
  int midx = mbase + colw;               // global m index (ms=0), += MT per mtile

  // fragment-major B pointer: wave's group pair g0 = (mbase>>4) + wave*2
  // frag (g, ks) block = 512 elems; group stride = 8*512 = 4096 elems.
  const unsigned short* Bp = Hmb + (size_t)((mbase >> 4) + wave * 2) * 4096 + (size_t)lane * 8;
#define LD(OFS) (*(const bf16x8*)(Bp + (OFS)))

// one MFMA k-step: A slots (KS*2+0 / KS*2+1) x named B frags
#define KSTEP(KS, BA, BB) do {                                                        \
    const bf16x8 a0_ = *(const bf16x8*)(Afs + (((KS) * 2 + 0) * 64 + lane) * 8);      \
    const bf16x8 a1_ = *(const bf16x8*)(Afs + (((KS) * 2 + 1) * 64 + lane) * 8);      \
    acc00 = __builtin_amdgcn_mfma_f32_16x16x32_bf16(a0_, BA, acc00, 0, 0, 0);         \
    acc01 = __builtin_amdgcn_mfma_f32_16x16x32_bf16(a0_, BB, acc01, 0, 0, 0);         \
    acc10 = __builtin_amdgcn_mfma_f32_16x16x32_bf16(a1_, BA, acc10, 0, 0, 0);         \
    acc11 = __builtin_amdgcn_mfma_f32_16x16x32_bf16(a1_, BB, acc11, 0, 0, 0);         \
  } while (0)

// score + sorted top-3 insert, unconditional (all tokens named vars)
#define SCOREU(ACC, R, YM, RO, GI, XQ, T0, T1, T2) do {                               \
    const float sv_ = fmaxf(fmaf(-2.f, (ACC)[R], (XQ) + (YM)), 0.f) * (RO);           \
    const unsigned long long pk_ =                                                     \
      (((unsigned long long)__float_as_uint(sv_)) << 32) | (unsigned int)(GI);         \
    if (pk_ < T2) {                                                                    \
      T2 = pk_;                                                                        \
      if (T2 < T1) { const unsigned long long x_ = T1; T1 = T2; T2 = x_; }             \
      if (T1 < T0) { const unsigned long long x_ = T0; T0 = T1; T1 = x_; }             \
    }                                                                                  \
  } while (0)

// masked variant (tail chunk only)
#define SCOREM(ACC, R, YM, RO, OK, GI, XQ, T0, T1, T2) do {                           \
    const float sv_ = fmaxf(fmaf(-2.f, (ACC)[R], (XQ) + (YM)), 0.f) * (RO);           \
    const unsigned long long pk_ =                                                     \
      (((unsigned long long)__float_as_uint(sv_)) << 32) | (unsigned int)(GI);         \
    if ((OK) && pk_ < T2) {                                                            \
      T2 = pk_;                                                                        \
      if (T2 < T1) { const unsigned long long x_ = T1; T1 = T2; T2 = x_; }             \
      if (T1 < T0) { const unsigned long long x_ = T0; T0 = T1; T1 = x_; }             \
    }                                                                                  \
  } while (0)

#define SCORE16U do {                                                                 \
    const float ym0 = aux0.x, ro0 = aux0.y;                                           \
    const float ym1 = aux1.x, ro1 = aux1.y;                                           \
    const int   gi0 = midx;                                                           \
    const int   gi1 = midx + 16;                                                      \
    SCOREU(acc00, 0, ym0, ro0, gi0, xq0, t0a, t0b, t0c);                              \
    SCOREU(acc00, 1, ym0, ro0, gi0, xq1, t1a, t1b, t1c);                              \
    SCOREU(acc00, 2, ym0, ro0, gi0, xq2, t2a, t2b, t2c);                              \
    SCOREU(acc00, 3, ym0, ro0, gi0, xq3, t3a, t3b, t3c);                              \
    SCOREU(acc01, 0, ym1, ro1, gi1, xq0, t0a, t0b, t0c);                              \
    SCOREU(acc01, 1, ym1, ro1, gi1, xq1, t1a, t1b, t1c);                              \
    SCOREU(acc01, 2, ym1, ro1, gi1, xq2, t2a, t2b, t2c);                              \
    SCOREU(acc01, 3, ym1, ro1, gi1, xq3, t3a, t3b, t3c);                              \
    SCOREU(acc10, 0, ym0, ro0, gi0, xq4, t4a, t4b, t4c);                              \
    SCOREU(acc10, 1, ym0, ro0, gi0, xq5, t5a, t5b, t5c);                              \
    SCOREU(acc10, 2, ym0, ro0, gi0, xq6, t6a, t6b, t6c);                              \
    SCOREU(acc10, 3, ym0, ro0, gi0, xq7, t7a, t7b, t7c);                              \
    SCOREU(acc11, 0, ym1, ro1, gi1, xq4, t4a, t4b, t4c);                              \
    SCOREU(acc11, 1, ym1, ro1, gi1, xq5, t5a, t5b, t5c);                              \
    SCOREU(acc11, 2, ym1, ro1, gi1, xq6, t6a, t6b, t6c);                              \
    SCOREU(acc11, 3, ym1, ro1, gi1, xq7, t7a, t7b, t7c);                              \
  } while (0)

#define SCORE16M(OK0, OK1) do {                                                       \
    const float ym0 = aux0.x, ro0 = aux0.y;                                           \
    const float ym1 = aux1.x, ro1 = aux1.y;                                           \
    const int   gi0 = midx;                                                           \
    const int   gi1 = midx + 16;                                                      \
    SCOREM(acc00, 0, ym0, ro0, OK0, gi0, xq0, t0a, t0b, t0c);                         \
    SCOREM(acc00, 1, ym0, ro0, OK0, gi0, xq1, t1a, t1b, t1c);                         \
    SCOREM(acc00, 2, ym0, ro0, OK0, gi0, xq2, t2a, t2b, t2c);                         \
    SCOREM(acc00, 3, ym0, ro0, OK0, gi0, xq3, t3a, t3b, t3c);                         \
    SCOREM(acc01, 0, ym1, ro1, OK1, gi1, xq0, t0a, t0b, t0c);                         \
    SCOREM(acc01, 1, ym1, ro1, OK1, gi1, xq1, t1a, t1b, t1c);                         \
    SCOREM(acc01, 2, ym1, ro1, OK1, gi1, xq2, t2a, t2b, t2c);                         \
    SCOREM(acc01, 3, ym1, ro1, OK1, gi1, xq3, t3a, t3b, t3c);                         \
    SCOREM(acc10, 0, ym0, ro0, OK0, gi0, xq4, t4a, t4b, t4c);                         \
    SCOREM(acc10, 1, ym0, ro0, OK0, gi0, xq5, t5a, t5b, t5c);                         \
    SCOREM(acc10, 2, ym0, ro0, OK0, gi0, xq6, t6a, t6b, t6c);                         \
    SCOREM(acc10, 3, ym0, ro0, OK0, gi0, xq7, t7a, t7b, t7c);                         \
    SCOREM(acc11, 0, ym1, ro1, OK1, gi1, xq4, t4a, t4b, t4c);                         \
    SCOREM(acc11, 1, ym1, ro1, OK1, gi1, xq5, t5a, t5b, t5c);                         \
    SCOREM(acc11, 2, ym1, ro1, OK1, gi1, xq6, t6a, t6b, t6c);                         \
    SCOREM(acc11, 3, ym1, ro1, OK1, gi1, xq7, t7a, t7b, t7c);                         \
  } while (0)

  if (c != NCHUNK - 1) {
    // ---- chunks 0..38: 10 full unmasked mtiles, half-tile pipeline ----
    // preload X = k-half0 of mtile 0 (X: ks0..3 of both 16-row groups)
    bf16x8 xA0 = LD(0),    xA1 = LD(512),  xA2 = LD(1024), xA3 = LD(1536);
    bf16x8 xB0 = LD(4096), xB1 = LD(4608), xB2 = LD(5120), xB3 = LD(5632);

    for (int mt = 0; mt < NMT - 1; ++mt) {   // mt 0..8: branch-free body
      // issue Y = k-half1 of current mtile
      bf16x8 yA0 = LD(2048), yA1 = LD(2560), yA2 = LD(3072), yA3 = LD(3584);
      bf16x8 yB0 = LD(6144), yB1 = LD(6656), yB2 = LD(7168), yB3 = LD(7680);
      const float2 aux0 = auxm[midx];
      const float2 aux1 = auxm[midx + 16];

      f32x4 acc00 = {0.f, 0.f, 0.f, 0.f};
      f32x4 acc01 = {0.f, 0.f, 0.f, 0.f};
      f32x4 acc10 = {0.f, 0.f, 0.f, 0.f};
      f32x4 acc11 = {0.f, 0.f, 0.f, 0.f};

      KSTEP(0, xA0, xB0);
      KSTEP(1, xA1, xB1);
      KSTEP(2, xA2, xB2);
      KSTEP(3, xA3, xB3);

      // advance, issue X of NEXT mtile (in flight across inserts)
      Bp += 8 * 4096;
      xA0 = LD(0);    xA1 = LD(512);  xA2 = LD(1024); xA3 = LD(1536);
      xB0 = LD(4096); xB1 = LD(4608); xB2 = LD(5120); xB3 = LD(5632);

      KSTEP(4, yA0, yB0);
      KSTEP(5, yA1, yB1);
      KSTEP(6, yA2, yB2);
      KSTEP(7, yA3, yB3);

      SCORE16U;
      midx += MT;
    }

    { // final mtile mt=9 (X preloaded, no further prefetch), unmasked
      bf16x8 yA0 = LD(2048), yA1 = LD(2560), yA2 = LD(3072), yA3 = LD(3584);
      bf16x8 yB0 = LD(6144), yB1 = LD(6656), yB2 = LD(7168), yB3 = LD(7680);
      const float2 aux0 = auxm[midx];
      const float2 aux1 = auxm[midx + 16];

      f32x4 acc00 = {0.f, 0.f, 0.f, 0.f};
      f32x4 acc01 = {0.f, 0.f, 0.f, 0.f};
      f32x4 acc10 = {0.f, 0.f, 0.f, 0.f};
      f32x4 acc11 = {0.f, 0.f, 0.f, 0.f};

      KSTEP(0, xA0, xB0);
      KSTEP(1, xA1, xB1);
      KSTEP(2, xA2, xB2);
      KSTEP(3, xA3, xB3);
      KSTEP(4, yA0, yB0);
      KSTEP(5, yA1, yB1);
      KSTEP(6, yA2, yB2);
      KSTEP(7, yA3, yB3);

      SCORE16U;
    }
  } else {
    // ---- tail chunk 39: rows 49920..49999 valid (80) -> 1 masked mtile ----
    // Reads stay within the padded 50048-row fragment region; junk cols are
    // masked (NaN-safe: mask is && before insert).
    const int vrem = N_M - mbase;               // 80
    const bool ok0 = colw < vrem;
    const bool ok1 = colw + 16 < vrem;

    bf16x8 xA0 = LD(0),    xA1 = LD(512),  xA2 = LD(1024), xA3 = LD(1536);
    bf16x8 xB0 = LD(4096), xB1 = LD(4608), xB2 = LD(5120), xB3 = LD(5632);
    bf16x8 yA0 = LD(2048), yA1 = LD(2560), yA2 = LD(3072), yA3 = LD(3584);
    bf16x8 yB0 = LD(6144), yB1 = LD(6656), yB2 = LD(7168), yB3 = LD(7680);
    const float2 aux0 = auxm[midx];
    const float2 aux1 = auxm[midx + 16];

    f32x4 acc00 = {0.f, 0.f, 0.f, 0.f};
    f32x4 acc01 = {0.f, 0.f, 0.f, 0.f};
    f32x4 acc10 = {0.f, 0.f, 0.f, 0.f};
    f32x4 acc11 = {0.f, 0.f, 0.f, 0.f};

    KSTEP(0, xA0, xB0);
    KSTEP(1, xA1, xB1);
    KSTEP(2, xA2, xB2);
    KSTEP(3, xA3, xB3);
    KSTEP(4, yA0, yB0);
    KSTEP(5, yA1, yB1);
    KSTEP(6, yA2, yB2);
    KSTEP(7, yA3, yB3);

    SCORE16M(ok0, ok1);
  }

#undef LD
#undef KSTEP
#undef SCOREU
#undef SCOREM
#undef SCORE16U
#undef SCORE16M

  // per-wave extraction: per query-row, 16 lanes x top-3 -> wave top-8.
  // (quads handle 4 query-rows in parallel; shfl offsets 1..8 stay in-quad)
#define EXTRACT_ROW(WIDX, T0, T1, T2) do {                                            \
    unsigned long long p0 = T0, p1 = T1, p2 = T2;                                     \
    for (int rd = 0; rd < CPC; ++rd) {                                                \
      unsigned long long lm = (p0 < p1) ? p0 : p1;                                    \
      lm = (p2 < lm) ? p2 : lm;                                                       \
      unsigned long long gm = lm;                                                     \
      for (int off = 1; off < 16; off <<= 1) {                                        \
        const unsigned long long o = __shfl_xor(gm, off);                             \
        gm = (o < gm) ? o : gm;                                                       \
      }                                                                               \
      if      (p0 == gm) p0 = ~0ULL;                                                  \
      else if (p1 == gm) p1 = ~0ULL;                                                  \
      else if (p2 == gm) p2 = ~0ULL;                                                  \
      if (lx == 0) wtop[wave][WIDX][rd] = gm;                                         \
    }                                                                                 \
  } while (0)

  EXTRACT_ROW(quad * 4 + 0,      t0a, t0b, t0c);
  EXTRACT_ROW(quad * 4 + 1,      t1a, t1b, t1c);
  EXTRACT_ROW(quad * 4 + 2,      t2a, t2b, t2c);
  EXTRACT_ROW(quad * 4 + 3,      t3a, t3b, t3c);
  EXTRACT_ROW(16 + quad * 4 + 0, t4a, t4b, t4c);
  EXTRACT_ROW(16 + quad * 4 + 1, t5a, t5b, t5c);
  EXTRACT_ROW(16 + quad * 4 + 2, t6a, t6b, t6c);
  EXTRACT_ROW(16 + quad * 4 + 3, t7a, t7b, t7c);
#undef EXTRACT_ROW
  __syncthreads();

  // cross-wave merge: 8 threads per query, 4 waves x 8 -> top-8 -> cand
  {
    const int qr = t >> 3;        // 0..31
    const int sp = t & 7;
    unsigned long long v0 = wtop[0][qr][sp];
    unsigned long long v1 = wtop[1][qr][sp];
    unsigned long long v2 = wtop[2][qr][sp];
    unsigned long long v3 = wtop[3][qr][sp];
    const size_t cbase = ((size_t)(q0 + qr) * NCHUNK + c) * CPC;
    for (int rd = 0; rd < CPC; ++rd) {
      unsigned long long lm = (v0 < v1) ? v0 : v1;
      const unsigned long long l2 = (v2 < v3) ? v2 : v3;
      lm = (l2 < lm) ? l2 : lm;
      unsigned long long gm = lm;
#pragma unroll
      for (int off = 1; off < 8; off <<= 1) {
        const unsigned long long o = __shfl_xor(gm, off);
        gm = (o < gm) ? o : gm;
      }
      if      (v0 == gm) v0 = ~0ULL;
      else if (v1 == gm) v1 = ~0ULL;
      else if (v2 == gm) v2 = ~0ULL;
      else if (v3 == gm) v3 = ~0ULL;
      if (sp == 0) {
        cand_s[cbase + rd] = __uint_as_float((unsigned int)(gm >> 32));
        cand_i[cbase + rd] = (int)(unsigned int)(gm & 0xffffffffu);
      }
    }
  }
}

// ---------------------------------------------------------------------------
// Finalize: per query, 256 threads (4 waves): parallel candidate merge
// 320 -> 4x16 -> top-16 (fp32 score, idx tie-break), fp64 rescore (4 cands
// per wave) -> exact top-8 order, softmax, parallel mask gather.
// ---------------------------------------------------------------------------
__global__ __launch_bounds__(256) void finalize_kernel(
    const float* __restrict__ Hq, const float* __restrict__ Hm,
    const float* __restrict__ masks,
    const float* __restrict__ cand_s, const int* __restrict__ cand_i,
    float* __restrict__ outW, float* __restrict__ outH)
{
  const int q    = blockIdx.x;
  const int t    = threadIdx.x;
  const int lane = t & 63;
  const int wave = t >> 6;

  __shared__ unsigned long long wtop[4][T16];
  __shared__ int    selIdx[T16];
  __shared__ double dArr[T16];
  __shared__ int    fin_i[KSEL];
  __shared__ double fin_d[KSEL];
  __shared__ double ew[KSEL];

  // phase 1: each wave takes 80 candidates -> its top-16 (indices unique)
  {
    const size_t base = (size_t)q * NC + (size_t)wave * (NC / 4);
    unsigned long long pk[2];
#pragma unroll
    for (int s = 0; s < 2; ++s) {
      const int c = lane + 64 * s;
      pk[s] = (c < NC / 4)
        ? ((((unsigned long long)__float_as_uint(cand_s[base + c])) << 32) | (unsigned int)cand_i[base + c])
        : ~0ULL;
    }
    for (int r = 0; r < T16; ++r) {
      unsigned long long lm = (pk[0] < pk[1]) ? pk[0] : pk[1];
      unsigned long long gm = lm;
#pragma unroll
      for (int off = 1; off < 64; off <<= 1) {
        unsigned long long o = __shfl_xor(gm, off);
        gm = (o < gm) ? o : gm;
      }
      bool done = false;
#pragma unroll
      for (int s = 0; s < 2; ++s) if (!done && pk[s] == gm) { pk[s] = ~0ULL; done = true; }
      if (lane == 0) wtop[wave][r] = gm;
    }
  }
  __syncthreads();

  // phase 2: wave 0 merges 64 -> global top-16
  if (wave == 0) {
    unsigned long long v = wtop[lane >> 4][lane & 15];
    for (int r = 0; r < T16; ++r) {
      unsigned long long gm = v;
#pragma unroll
      for (int off = 1; off < 64; off <<= 1) {
        unsigned long long o = __shfl_xor(gm, off);
        gm = (o < gm) ? o : gm;
      }
      if (v == gm) v = ~0ULL;
      if (lane == 0) selIdx[r] = (int)(unsigned int)(gm & 0xffffffffULL);
    }
  }
  __syncthreads();

  // phase 3: fp64 rescore, 4 candidates per wave
  const float4 q4 = *(const float4*)(Hq + (size_t)q * DIM + 4 * lane);
  double xp_ = (double)q4.x * q4.x + (double)q4.y * q4.y + (double)q4.z * q4.z + (double)q4.w * q4.w;
#pragma unroll
  for (int off = 1; off < 64; off <<= 1) xp_ += __shfl_xor(xp_, off);
  const double xsq = xp_;

  for (int r = wave; r < T16; r += 4) {
    const int cidx = selIdx[r];
    const float4 m4 = *(const float4*)(Hm + (size_t)cidx * DIM + 4 * lane);
    double dp = (double)q4.x * m4.x + (double)q4.y * m4.y + (double)q4.z * m4.z + (double)q4.w * m4.w;
    double yp = (double)m4.x * m4.x + (double)m4.y * m4.y + (double)m4.z * m4.z + (double)m4.w * m4.w;
#pragma unroll
    for (int off = 1; off < 64; off <<= 1) { dp += __shfl_xor(dp, off); yp += __shfl_xor(yp, off); }
    if (lane == 0) {
      double diff = xsq + yp - 2.0 * dp; if (diff < 0.0) diff = 0.0;
      double den = (1.0 - xsq) * (1.0 - yp);
      double arg = 1.0 + 2.0 * diff / (den + 1e-8);
      const double lo = 1.0 + 1e-6;
      if (arg < lo) arg = lo;
      dArr[r] = log(arg + sqrt(arg * arg - 1.0));   // arccosh
    }
  }
  __syncthreads();

  // phase 4: exact rank (dist, idx) -> top-8, softmax
  if (t < T16) {
    const double dj = dArr[t]; const int ij = selIdx[t];
    int rank = 0;
#pragma unroll
    for (int i = 0; i < T16; ++i)
      rank += (dArr[i] < dj || (dArr[i] == dj && selIdx[i] < ij)) ? 1 : 0;
    if (rank < KSEL) { fin_d[rank] = dj; fin_i[rank] = ij; }
  }
  __syncthreads();
  if (t < KSEL) ew[t] = exp(fin_d[0] - fin_d[t]);
  __syncthreads();
  if (t < KSEL) {
    double ssum = 0.0;
#pragma unroll
    for (int i = 0; i < KSEL; ++i) ssum += ew[i];
    outW[(size_t)q * KSEL + t] = (float)(ew[t] / ssum);
  }

  // phase 5: mask gather, 32 threads per output row
  const int g  = t >> 5;
  const int l0 = t & 31;
  const int row = fin_i[g];
  for (int l = l0; l < ATOMS; l += 32)
    outH[((size_t)q * KSEL + g) * ATOMS + l] = masks[(size_t)row * ATOMS + l];
}

// ---------------------------------------------------------------------------
extern "C" void kernel_launch(void* const* d_in, const int* in_sizes, int n_in,
                              void* d_out, int out_size, void* d_ws, size_t ws_size,
                              hipStream_t stream) {
  const float* Q     = (const float*)d_in[0];   // [1024,256]
  const float* M     = (const float*)d_in[1];   // [50000,256]
  const float* masks = (const float*)d_in[2];   // [50000,200]
  const float* W     = (const float*)d_in[3];   // [256,256]
  const float* bv    = (const float*)d_in[4];   // [256]
  // d_in[5] = k (always 8, hard-coded)

  char* w = (char*)d_ws;
  float*          Hq   = (float*)(w);                       //  1,048,576 B
  float*          Hm   = (float*)(w + 1048576);             // 51,200,000 B
  unsigned short* Hqb  = (unsigned short*)(w + 52248576);   //    524,288 B (frag-major, 64 groups)
  unsigned short* Hmb  = (unsigned short*)(w + 52772864);   // 25,624,576 B (frag-major, 3128 groups = 50048 rows)
  float2*         auxq = (float2*)(w + 78397440);           //      8,192 B
  float2*         auxm = (float2*)(w + 78405632);           //    400,384 B (padded to 50048)
  float*          cs   = (float*)(w + 78806016);            //  1,310,720 B
  int*            cix  = (int*)(w + 80116736);              //  1,310,720 B -> 81,427,456 total

  // Wt bf16 planes alias the cand_s region (dead until score_kernel writes it)
  unsigned short* Wt1 = (unsigned short*)(w + 78806016);    // 3 x 131,072 B
  unsigned short* Wt2 = Wt1 + DIM * DIM;
  unsigned short* Wt3 = Wt2 + DIM * DIM;

  wsplit_kernel<<<DIM, DIM, 0, stream>>>(W, Wt1, Wt2, Wt3);
  transform_kernel<<<(B_Q + TROWS - 1) / TROWS, 1024, 0, stream>>>(Q, B_Q, Wt1, Wt2, Wt3, bv, Hq, Hqb, auxq);
  transform_kernel<<<(N_M + TROWS - 1) / TROWS, 1024, 0, stream>>>(M, N_M, Wt1, Wt2, Wt3, bv, Hm, Hmb, auxm);
  score_kernel<<<dim3(NCHUNK, B_Q / 32), 256, 0, stream>>>(Hqb, Hmb, auxq, auxm, cs, cix);
  finalize_kernel<<<B_Q, 256, 0, stream>>>(Hq, Hm, masks, cs, cix,
                                           (float*)d_out, (float*)d_out + (size_t)B_Q * KSEL);
}

// Round 7
// 347.099 us; speedup vs baseline: 1.1514x; 1.0373x over previous
//
#include <hip/hip_runtime.h>
#include <hip/hip_bf16.h>
#include <math.h>
#include <float.h>

#define B_Q   1024
#define N_M   50000
#define DIM   256
#define ATOMS 200
#define KSEL  8
#define NCHUNK 40
#define CHUNK  1280       // rows per chunk (16-aligned for fragment groups)
#define MT    128
#define NMT   10          // CHUNK/MT exactly
#define CPC   8           // candidates kept per (query, chunk)
#define NC    (NCHUNK * CPC)   // 320 candidates per query
#define T16   16          // finalize rescore set
#define TROWS 64          // transform rows per block
#define APX   264         // A-plane LDS row stride in bf16 elems (528B, 16B-aligned)

typedef __attribute__((ext_vector_type(8))) short bf16x8;
typedef __attribute__((ext_vector_type(4))) float f32x4;

static __device__ inline unsigned short f2bf(float f) {
  __hip_bfloat16 h = __float2bfloat16(f);   // RNE
  return *reinterpret_cast<unsigned short*>(&h);
}

// RNE 3-way split (one-time W prep): x ~= s1+s2+s3, residual <= 2^-27 |x|
static __device__ inline void split3(float x, unsigned short& s1,
                                     unsigned short& s2, unsigned short& s3) {
  __hip_bfloat16 b1 = __float2bfloat16(x);
  float f1 = __bfloat162float(b1);
  float r1 = x - f1;
  __hip_bfloat16 b2 = __float2bfloat16(r1);
  float f2 = __bfloat162float(b2);
  __hip_bfloat16 b3 = __float2bfloat16(r1 - f2);
  s1 = *reinterpret_cast<unsigned short*>(&b1);
  s2 = *reinterpret_cast<unsigned short*>(&b2);
  s3 = *reinterpret_cast<unsigned short*>(&b3);
}

// Truncation 3-way split (hot path, 2 VALU/tier): residual <= 2^-24 |x|.
static __device__ inline void split3t(float x, unsigned short& s1,
                                      unsigned short& s2, unsigned short& s3) {
  const unsigned u = __float_as_uint(x);
  s1 = (unsigned short)(u >> 16);
  const float f1 = __uint_as_float(u & 0xffff0000u);
  const float r1 = x - f1;                       // exact
  const unsigned v = __float_as_uint(r1);
  s2 = (unsigned short)(v >> 16);
  const float f2 = __uint_as_float(v & 0xffff0000u);
  const float r2 = r1 - f2;                      // exact
  s3 = (unsigned short)(__float_as_uint(r2) >> 16);
}

// fp32 tanh via HW v_exp_f32 (~1ulp): rel err ~1.5e-7.
static __device__ inline float tanh32(float z) {
  float tz = fabsf(z) * 2.885390082f;           // 2|z|*log2(e)
  tz = fminf(tz, 120.f);
  const float E = __builtin_amdgcn_exp2f(tz);   // e^{2|z|}
  const float T = 1.f - 2.f / (E + 1.f);
  return (z >= 0.f) ? T : -T;
}

// ---------------------------------------------------------------------------
// W pre-split: Wt planes [n][k] (transposed) as bf16 triple. 256x256, tiny.
// ---------------------------------------------------------------------------
__global__ __launch_bounds__(256) void wsplit_kernel(
    const float* __restrict__ W,
    unsigned short* __restrict__ Wt1, unsigned short* __restrict__ Wt2,
    unsigned short* __restrict__ Wt3)
{
  const int n = blockIdx.x;
  const int k = threadIdx.x;
  unsigned short s1, s2, s3;
  split3(W[(size_t)k * DIM + n], s1, s2, s3);
  Wt1[(size_t)n * DIM + k] = s1;
  Wt2[(size_t)n * DIM + k] = s2;
  Wt3[(size_t)n * DIM + k] = s3;
}

// ---------------------------------------------------------------------------
// Transform: H = to_poincare(X @ W + b); X@W via bf16 MFMA, 3-way Dekker
// split (6 product orders) chained into one fp32 accumulator per m-subtile.
// Hb written in MFMA B-FRAGMENT-MAJOR layout:
//   Frag[g][ks][lane][j]  (elem off = ((g*8+ks)*64 + lane)*8 + j)
//   g=row>>4, ks=col>>5, lane=((col>>3)&3)*16 + (row&15), j=col&7.
// Makes score_kernel's B/A loads lane-contiguous (1KB/wave, coalesced) —
// round-4 PMC showed the row-scattered pattern capped at ~8.7 B/cyc/CU;
// round-6 confirmed coalescing lifted it to ~29 B/cyc/CU (154 -> 110 us).
// ---------------------------------------------------------------------------
__global__ __launch_bounds__(1024) void transform_kernel(
    const float* __restrict__ X, int nrows,
    const unsigned short* __restrict__ Wt1, const unsigned short* __restrict__ Wt2,
    const unsigned short* __restrict__ Wt3, const float* __restrict__ bvec,
    float* __restrict__ H, unsigned short* __restrict__ Hb,
    float2* __restrict__ aux)
{
  __shared__ __align__(16) unsigned short X1s[TROWS * APX];
  __shared__ __align__(16) unsigned short X2s[TROWS * APX];
  __shared__ __align__(16) unsigned short X3s[TROWS * APX];
  __shared__ float red[16][TROWS];
  __shared__ float sArr[TROWS];

  const int t    = threadIdx.x;
  const int lane = t & 63;
  const int wave = t >> 6;
  const int row0 = blockIdx.x * TROWS;

  // stage + split X tile [64][256]: thread owns (row r, 16 cols at c0)
  {
    const int r  = t >> 4;
    const int c0 = (t & 15) * 16;
    int gr = row0 + r; if (gr >= nrows) gr = nrows - 1;   // clamp (stores guarded)
    const float4* src = (const float4*)(X + (size_t)gr * DIM + c0);
    bf16x8 p1[2], p2[2], p3[2];
#pragma unroll
    for (int half = 0; half < 2; ++half) {
#pragma unroll
      for (int v = 0; v < 2; ++v) {
        const float4 x4 = src[half * 2 + v];
        const float xv[4] = {x4.x, x4.y, x4.z, x4.w};
#pragma unroll
        for (int i = 0; i < 4; ++i) {
          unsigned short s1, s2, s3;
          split3t(xv[i], s1, s2, s3);
          p1[half][v * 4 + i] = (short)s1;
          p2[half][v * 4 + i] = (short)s2;
          p3[half][v * 4 + i] = (short)s3;
        }
      }
      *(bf16x8*)(X1s + r * APX + c0 + half * 8) = p1[half];
      *(bf16x8*)(X2s + r * APX + c0 + half * 8) = p2[half];
      *(bf16x8*)(X3s + r * APX + c0 + half * 8) = p3[half];
    }
  }
  __syncthreads();

  const int lx   = lane & 15;    // A row m / B col n / D col
  const int quad = lane >> 4;    // k-group / D row-quad
  const int n0   = wave * 16;    // this wave's output col-tile

  f32x4 acc[4];
#pragma unroll
  for (int ms = 0; ms < 4; ++ms) { acc[ms][0] = 0.f; acc[ms][1] = 0.f; acc[ms][2] = 0.f; acc[ms][3] = 0.f; }

  const size_t brow = (size_t)(n0 + lx) * DIM + quad * 8;
  bf16x8 b1c = *(const bf16x8*)(Wt1 + brow);
  bf16x8 b2c = *(const bf16x8*)(Wt2 + brow);
  bf16x8 b3c = *(const bf16x8*)(Wt3 + brow);

#pragma unroll
  for (int ks = 0; ks < 8; ++ks) {
    bf16x8 b1n, b2n, b3n;
    if (ks < 7) {                       // prefetch next k-step's B
      const size_t nb = brow + (ks + 1) * 32;
      b1n = *(const bf16x8*)(Wt1 + nb);
      b2n = *(const bf16x8*)(Wt2 + nb);
      b3n = *(const bf16x8*)(Wt3 + nb);
    }
    const int ko = ks * 32 + quad * 8;
#pragma unroll
    for (int ms = 0; ms < 4; ++ms) {
      const int ar = (ms * 16 + lx) * APX + ko;
      const bf16x8 a1 = *(const bf16x8*)(X1s + ar);
      const bf16x8 a2 = *(const bf16x8*)(X2s + ar);
      const bf16x8 a3 = *(const bf16x8*)(X3s + ar);
      acc[ms] = __builtin_amdgcn_mfma_f32_16x16x32_bf16(a1, b1c, acc[ms], 0, 0, 0);
      acc[ms] = __builtin_amdgcn_mfma_f32_16x16x32_bf16(a1, b2c, acc[ms], 0, 0, 0);
      acc[ms] = __builtin_amdgcn_mfma_f32_16x16x32_bf16(a2, b1c, acc[ms], 0, 0, 0);
      acc[ms] = __builtin_amdgcn_mfma_f32_16x16x32_bf16(a1, b3c, acc[ms], 0, 0, 0);
      acc[ms] = __builtin_amdgcn_mfma_f32_16x16x32_bf16(a2, b2c, acc[ms], 0, 0, 0);
      acc[ms] = __builtin_amdgcn_mfma_f32_16x16x32_bf16(a3, b1c, acc[ms], 0, 0, 0);
    }
    b1c = b1n; b2c = b2n; b3c = b3n;
  }

  // bias + tanh: lane holds rows ms*16+quad*4+r, col n0+lx (bias col-constant)
  const float bb = bvec[n0 + lx];
  float h[4][4];
#pragma unroll
  for (int ms = 0; ms < 4; ++ms)
#pragma unroll
    for (int r = 0; r < 4; ++r)
      h[ms][r] = tanh32(acc[ms][r] + bb);

  // row-norm partial over this wave's 16 cols (shuffle over lx)
  float p[4][4];
#pragma unroll
  for (int ms = 0; ms < 4; ++ms)
#pragma unroll
    for (int r = 0; r < 4; ++r) p[ms][r] = h[ms][r] * h[ms][r];
#pragma unroll
  for (int off = 1; off < 16; off <<= 1)
#pragma unroll
    for (int ms = 0; ms < 4; ++ms)
#pragma unroll
      for (int r = 0; r < 4; ++r) p[ms][r] += __shfl_xor(p[ms][r], off);
  if (lx == 0)
#pragma unroll
    for (int ms = 0; ms < 4; ++ms)
#pragma unroll
      for (int r = 0; r < 4; ++r) red[wave][ms * 16 + quad * 4 + r] = p[ms][r];
  __syncthreads();

  if (t < TROWS) {
    float nsq = 0.f;
#pragma unroll
    for (int w = 0; w < 16; ++w) nsq += red[w][t];
    const float nrm = sqrtf(nsq);
    sArr[t] = (nrm > 0.95f) ? (0.95f / nrm) : 1.f;
  }
  __syncthreads();

  float u[4][4];
#pragma unroll
  for (int ms = 0; ms < 4; ++ms)
#pragma unroll
    for (int r = 0; r < 4; ++r) {
      const float sc = sArr[ms * 16 + quad * 4 + r];
      u[ms][r] = h[ms][r] * sc;
      p[ms][r] = u[ms][r] * u[ms][r];
    }
#pragma unroll
  for (int off = 1; off < 16; off <<= 1)
#pragma unroll
    for (int ms = 0; ms < 4; ++ms)
#pragma unroll
      for (int r = 0; r < 4; ++r) p[ms][r] += __shfl_xor(p[ms][r], off);
  if (lx == 0)
#pragma unroll
    for (int ms = 0; ms < 4; ++ms)
#pragma unroll
      for (int r = 0; r < 4; ++r) red[wave][ms * 16 + quad * 4 + r] = p[ms][r];

  // stores: H fp32 (row-major) + Hb bf16 (FRAGMENT-MAJOR, guarded rows)
  const int colv = n0 + lx;
  const int ksb  = colv >> 5;                         // fragment k-slot
  const int qoff = ((colv >> 3) & 3) * 128 + (colv & 7);  // quad*16 lanes *8 + j
#pragma unroll
  for (int ms = 0; ms < 4; ++ms)
#pragma unroll
    for (int r = 0; r < 4; ++r) {
      const int grow = row0 + ms * 16 + quad * 4 + r;
      if (grow < nrows) {
        H[(size_t)grow * DIM + colv] = u[ms][r];
        Hb[((size_t)((row0 >> 4) + ms) * 8 + ksb) * 512 + qoff + (quad * 4 + r) * 8]
            = f2bf(u[ms][r]);
      }
    }
  __syncthreads();
  if (t < TROWS) {
    const int grow = row0 + t;
    if (grow < nrows) {
      float ysq = 0.f;
#pragma unroll
      for (int w = 0; w < 16; ++w) ysq += red[w][t];
      aux[grow] = make_float2(ysq, 1.f / (1.f - ysq));
    }
  }
}

// ---------------------------------------------------------------------------
// Score (MFMA), v7: v5 coalesced pipeline + U32 PACKED KEYS + MIN/MAX INSERT.
// Round-6 PMC: coalescing worked (154->110us, 29 B/cyc/CU) but VALUBusy 45%
// is now the top pipe — the u64 sorted-insert (cmp + 8 cndmask) dominates.
// v7: per-lane candidate key = (fp32 score bits & ~31) | (mt*2+ms).
//  - idx fits 5 bits because lane/wave/chunk are implicit; decode at
//    extraction: gi = mbase + wave*32 + lx + mt*128 + ms*16.
//  - score truncated to 27 bits (rel step 2e-6) — selection already
//    tolerates ~2.5e-4 bf16-dot noise, so this is free; fp64 rescore in
//    finalize fixes exact order.
//  - insert = branch-free 5-op min/max network on sorted triple (keep 3
//    smallest): a'=min(a,x); t=max(a,x); b'=min(b,t); u=max(b,t);
//    c'=min(c,u). 5 VALU vs 13, and top-3 state 24 u32 vs 24 u64.
//  - scores >= 0 via fmax -> uint order == float order; RNE exact
//    cancellation gives +0 (never -0).
// Tail chunk masks invalid cols by cndmask key->0xFFFFFFFF BEFORE insert
// (also NaN-safe). Extraction rebuilds u64 (key<<32|gi) so the equality-pop
// butterfly merge keeps globally-unique keys. Merge/finalize unchanged.
// ---------------------------------------------------------------------------
__global__ __launch_bounds__(256) void score_kernel(
    const unsigned short* __restrict__ Hqb, const unsigned short* __restrict__ Hmb,
    const float2* __restrict__ auxq, const float2* __restrict__ auxm,
    float* __restrict__ cand_s, int* __restrict__ cand_i)
{
  __shared__ __align__(16) unsigned short Afs[16 * 64 * 8]; // 16 KB, frag-order
  __shared__ unsigned long long wtop[4][32][CPC];           // 8 KB

  const int t    = threadIdx.x;
  const int lane = t & 63;
  const int wave = t >> 6;
  const int q0   = blockIdx.y * 32;
  const int c    = blockIdx.x;
  const int mbase = c * CHUNK;
  const int lx   = lane & 15;
  const int quad = lane >> 4;

  // stage A fragments into LDS (slot = ks*2+qs; frag-major source, coalesced)
#pragma unroll
  for (int i = 0; i < 4; ++i) {
    const int sl = wave * 4 + i;
    const int ks = sl >> 1, qs = sl & 1;
    const bf16x8 a = *(const bf16x8*)(Hqb + ((size_t)((q0 >> 4) + qs) * 8 + ks) * 512 + (size_t)lane * 8);
    *(bf16x8*)(Afs + ((size_t)sl * 64 + lane) * 8) = a;
  }
  // per-row query norms (row = qs*4+r; rows 0-3 -> qs=0, rows 4-7 -> qs=1)
  const float xq0 = auxq[q0 +      quad * 4 + 0].x;
  const float xq1 = auxq[q0 +      quad * 4 + 1].x;
  const float xq2 = auxq[q0 +      quad * 4 + 2].x;
  const float xq3 = auxq[q0 +      quad * 4 + 3].x;
  const float xq4 = auxq[q0 + 16 + quad * 4 + 0].x;
  const float xq5 = auxq[q0 + 16 + quad * 4 + 1].x;
  const float xq6 = auxq[q0 + 16 + quad * 4 + 2].x;
  const float xq7 = auxq[q0 + 16 + quad * 4 + 3].x;
  __syncthreads();          // the ONLY pre-merge barrier

  // 24 named packed u32 top-3 keys (sorted ascending: a <= b <= c)
  unsigned t0a=0xFFFFFFFFu,t0b=0xFFFFFFFFu,t0c=0xFFFFFFFFu;
  unsigned t1a=0xFFFFFFFFu,t1b=0xFFFFFFFFu,t1c=0xFFFFFFFFu;
  unsigned t2a=0xFFFFFFFFu,t2b=0xFFFFFFFFu,t2c=0xFFFFFFFFu;
  unsigned t3a=0xFFFFFFFFu,t3b=0xFFFFFFFFu,t3c=0xFFFFFFFFu;
  unsigned t4a=0xFFFFFFFFu,t4b=0xFFFFFFFFu,t4c=0xFFFFFFFFu;
  unsigned t5a=0xFFFFFFFFu,t5b=0xFFFFFFFFu,t5c=0xFFFFFFFFu;
  unsigned t6a=0xFFFFFFFFu,t6b=0xFFFFFFFFu,t6c=0xFFFFFFFFu;
  unsigned t7a=0xFFFFFFFFu,t7b=0xFFFFFFFFu,t7c=0xFFFFFFFFu;

  const int colw = wave * 32 + lx;       // within-128-tile column, ms=0

  // fragment-major B pointer: wave's group pair g0 = (mbase>>4) + wave*2
  // frag (g, ks) block = 512 elems; group stride = 8*512 = 4096 elems.
  const unsigned short* Bp = Hmb + (size_t)((mbase >> 4) + wave * 2) * 4096 + (size_t)lane * 8;
#define LD(OFS) (*(const bf16x8*)(Bp + (OFS)))

// one MFMA k-step: A slots (KS*2+0 / KS*2+1) x named B frags
#define KSTEP(KS, BA, BB) do {                                                        \
    const bf16x8 a0_ = *(const bf16x8*)(Afs + (((KS) * 2 + 0) * 64 + lane) * 8);      \
    const bf16x8 a1_ = *(const bf16x8*)(Afs + (((KS) * 2 + 1) * 64 + lane) * 8);      \
    acc00 = __builtin_amdgcn_mfma_f32_16x16x32_bf16(a0_, BA, acc00, 0, 0, 0);         \
    acc01 = __builtin_amdgcn_mfma_f32_16x16x32_bf16(a0_, BB, acc01, 0, 0, 0);         \
    acc10 = __builtin_amdgcn_mfma_f32_16x16x32_bf16(a1_, BA, acc10, 0, 0, 0);         \
    acc11 = __builtin_amdgcn_mfma_f32_16x16x32_bf16(a1_, BB, acc11, 0, 0, 0);         \
  } while (0)

// u32-key score + 5-op sorted-insert (keep 3 smallest), unconditional
#define SCOREU(ACC, R, YM, RO, CODE, XQ, T0, T1, T2) do {                             \
    const float sv_ = fmaxf(fmaf(-2.f, (ACC)[R], (XQ) + (YM)), 0.f) * (RO);           \
    const unsigned k_ = (__float_as_uint(sv_) & 0xFFFFFFE0u) | (unsigned)(CODE);      \
    const unsigned a_ = min(T0, k_);                                                  \
    const unsigned x_ = max(T0, k_);                                                  \
    const unsigned b_ = min(T1, x_);                                                  \
    const unsigned y_ = max(T1, x_);                                                  \
    const unsigned c_ = min(T2, y_);                                                  \
    T0 = a_; T1 = b_; T2 = c_;                                                        \
  } while (0)

// masked variant (tail chunk only): invalid -> 0xFFFFFFFF sentinel
#define SCOREM(ACC, R, YM, RO, OK, CODE, XQ, T0, T1, T2) do {                         \
    const float sv_ = fmaxf(fmaf(-2.f, (ACC)[R], (XQ) + (YM)), 0.f) * (RO);           \
    const unsigned kr_ = (__float_as_uint(sv_) & 0xFFFFFFE0u) | (unsigned)(CODE);     \
    const unsigned k_ = (OK) ? kr_ : 0xFFFFFFFFu;                                     \
    const unsigned a_ = min(T0, k_);                                                  \
    const unsigned x_ = max(T0, k_);                                                  \
    const unsigned b_ = min(T1, x_);                                                  \
    const unsigned y_ = max(T1, x_);                                                  \
    const unsigned c_ = min(T2, y_);                                                  \
    T0 = a_; T1 = b_; T2 = c_;                                                        \
  } while (0)

#define SCORE16U(C0, C1) do {                                                         \
    const float ym0 = aux0.x, ro0 = aux0.y;                                           \
    const float ym1 = aux1.x, ro1 = aux1.y;                                           \
    SCOREU(acc00, 0, ym0, ro0, C0, xq0, t0a, t0b, t0c);                               \
    SCOREU(acc00, 1, ym0, ro0, C0, xq1, t1a, t1b, t1c);                               \
    SCOREU(acc00, 2, ym0, ro0, C0, xq2, t2a, t2b, t2c);                               \
    SCOREU(acc00, 3, ym0, ro0, C0, xq3, t3a, t3b, t3c);                               \
    SCOREU(acc01, 0, ym1, ro1, C1, xq0, t0a, t0b, t0c);                               \
    SCOREU(acc01, 1, ym1, ro1, C1, xq1, t1a, t1b, t1c);                               \
    SCOREU(acc01, 2, ym1, ro1, C1, xq2, t2a, t2b, t2c);                               \
    SCOREU(acc01, 3, ym1, ro1, C1, xq3, t3a, t3b, t3c);                               \
    SCOREU(acc10, 0, ym0, ro0, C0, xq4, t4a, t4b, t4c);                               \
    SCOREU(acc10, 1, ym0, ro0, C0, xq5, t5a, t5b, t5c);                               \
    SCOREU(acc10, 2, ym0, ro0, C0, xq6, t6a, t6b, t6c);                               \
    SCOREU(acc10, 3, ym0, ro0, C0, xq7, t7a, t7b, t7c);                               \
    SCOREU(acc11, 0, ym1, ro1, C1, xq4, t4a, t4b, t4c);                               \
    SCOREU(acc11, 1, ym1, ro1, C1, xq5, t5a, t5b, t5c);                               \
    SCOREU(acc11, 2, ym1, ro1, C1, xq6, t6a, t6b, t6c);                               \
    SCOREU(acc11, 3, ym1, ro1, C1, xq7, t7a, t7b, t7c);                               \
  } while (0)

#define SCORE16M(OK0, OK1, C0, C1) do {                                               \
    const float ym0 = aux0.x, ro0 = aux0.y;                                           \
    const float ym1 = aux1.x, ro1 = aux1.y;                                           \
    SCOREM(acc00, 0, ym0, ro0, OK0, C0, xq0, t0a, t0b, t0c);                          \
    SCOREM(acc00, 1, ym0, ro0, OK0, C0, xq1, t1a, t1b, t1c);                          \
    SCOREM(acc00, 2, ym0, ro0, OK0, C0, xq2, t2a, t2b, t2c);                          \
    SCOREM(acc00, 3, ym0, ro0, OK0, C0, xq3, t3a, t3b, t3c);                          \
    SCOREM(acc01, 0, ym1, ro1, OK1, C1, xq0, t0a, t0b, t0c);                          \
    SCOREM(acc01, 1, ym1, ro1, OK1, C1, xq1, t1a, t1b, t1c);                          \
    SCOREM(acc01, 2, ym1, ro1, OK1, C1, xq2, t2a, t2b, t2c);                          \
    SCOREM(acc01, 3, ym1, ro1, OK1, C1, xq3, t3a, t3b, t3c);                          \
    SCOREM(acc10, 0, ym0, ro0, OK0, C0, xq4, t4a, t4b, t4c);                          \
    SCOREM(acc10, 1, ym0, ro0, OK0, C0, xq5, t5a, t5b, t5c);                          \
    SCOREM(acc10, 2, ym0, ro0, OK0, C0, xq6, t6a, t6b, t6c);                          \
    SCOREM(acc10, 3, ym0, ro0, OK0, C0, xq7, t7a, t7b, t7c);                          \
    SCOREM(acc11, 0, ym1, ro1, OK1, C1, xq4, t4a, t4b, t4c);                          \
    SCOREM(acc11, 1, ym1, ro1, OK1, C1, xq5, t5a, t5b, t5c);                          \
    SCOREM(acc11, 2, ym1, ro1, OK1, C1, xq6, t6a, t6b, t6c);                          \
    SCOREM(acc11, 3, ym1, ro1, OK1, C1, xq7, t7a, t7b, t7c);                          \
  } while (0)

  if (c != NCHUNK - 1) {
    // ---- chunks 0..38: 10 full unmasked mtiles, half-tile pipeline ----
    int midx = mbase + colw;   // only for aux addressing
    // preload X = k-half0 of mtile 0 (ks0..3 of both 16-row groups)
    bf16x8 xA0 = LD(0),    xA1 = LD(512),  xA2 = LD(1024), xA3 = LD(1536);
    bf16x8 xB0 = LD(4096), xB1 = LD(4608), xB2 = LD(5120), xB3 = LD(5632);

    for (int mt = 0; mt < NMT - 1; ++mt) {   // mt 0..8: branch-free body
      // issue Y = k-half1 of current mtile
      bf16x8 yA0 = LD(2048), yA1 = LD(2560), yA2 = LD(3072), yA3 = LD(3584);
      bf16x8 yB0 = LD(6144), yB1 = LD(6656), yB2 = LD(7168), yB3 = LD(7680);
      const float2 aux0 = auxm[midx];
      const float2 aux1 = auxm[midx + 16];

      f32x4 acc00 = {0.f, 0.f, 0.f, 0.f};
      f32x4 acc01 = {0.f, 0.f, 0.f, 0.f};
      f32x4 acc10 = {0.f, 0.f, 0.f, 0.f};
      f32x4 acc11 = {0.f, 0.f, 0.f, 0.f};

      KSTEP(0, xA0, xB0);
      KSTEP(1, xA1, xB1);
      KSTEP(2, xA2, xB2);
      KSTEP(3, xA3, xB3);

      // advance, issue X of NEXT mtile (in flight across inserts)
      Bp += 8 * 4096;
      xA0 = LD(0);    xA1 = LD(512);  xA2 = LD(1024); xA3 = LD(1536);
      xB0 = LD(4096); xB1 = LD(4608); xB2 = LD(5120); xB3 = LD(5632);

      KSTEP(4, yA0, yB0);
      KSTEP(5, yA1, yB1);
      KSTEP(6, yA2, yB2);
      KSTEP(7, yA3, yB3);

      SCORE16U(mt * 2, mt * 2 + 1);
      midx += MT;
    }

    { // final mtile mt=9 (X preloaded, no further prefetch), unmasked
      bf16x8 yA0 = LD(2048), yA1 = LD(2560), yA2 = LD(3072), yA3 = LD(3584);
      bf16x8 yB0 = LD(6144), yB1 = LD(6656), yB2 = LD(7168), yB3 = LD(7680);
      const float2 aux0 = auxm[midx];
      const float2 aux1 = auxm[midx + 16];

      f32x4 acc00 = {0.f, 0.f, 0.f, 0.f};
      f32x4 acc01 = {0.f, 0.f, 0.f, 0.f};
      f32x4 acc10 = {0.f, 0.f, 0.f, 0.f};
      f32x4 acc11 = {0.f, 0.f, 0.f, 0.f};

      KSTEP(0, xA0, xB0);
      KSTEP(1, xA1, xB1);
      KSTEP(2, xA2, xB2);
      KSTEP(3, xA3, xB3);
      KSTEP(4, yA0, yB0);
      KSTEP(5, yA1, yB1);
      KSTEP(6, yA2, yB2);
      KSTEP(7, yA3, yB3);

      SCORE16U((NMT - 1) * 2, (NMT - 1) * 2 + 1);
    }
  } else {
    // ---- tail chunk 39: rows 49920..49999 valid (80) -> 1 masked mtile ----
    // Reads stay within the padded 50048-row fragment region; junk cols
    // (incl. possible NaN) cndmask'd to sentinel BEFORE insert.
    const int vrem = N_M - mbase;               // 80
    const bool ok0 = colw < vrem;
    const bool ok1 = colw + 16 < vrem;
    const int midx = mbase + colw;

    bf16x8 xA0 = LD(0),    xA1 = LD(512),  xA2 = LD(1024), xA3 = LD(1536);
    bf16x8 xB0 = LD(4096), xB1 = LD(4608), xB2 = LD(5120), xB3 = LD(5632);
    bf16x8 yA0 = LD(2048), yA1 = LD(2560), yA2 = LD(3072), yA3 = LD(3584);
    bf16x8 yB0 = LD(6144), yB1 = LD(6656), yB2 = LD(7168), yB3 = LD(7680);
    const float2 aux0 = auxm[midx];
    const float2 aux1 = auxm[midx + 16];

    f32x4 acc00 = {0.f, 0.f, 0.f, 0.f};
    f32x4 acc01 = {0.f, 0.f, 0.f, 0.f};
    f32x4 acc10 = {0.f, 0.f, 0.f, 0.f};
    f32x4 acc11 = {0.f, 0.f, 0.f, 0.f};

    KSTEP(0, xA0, xB0);
    KSTEP(1, xA1, xB1);
    KSTEP(2, xA2, xB2);
    KSTEP(3, xA3, xB3);
    KSTEP(4, yA0, yB0);
    KSTEP(5, yA1, yB1);
    KSTEP(6, yA2, yB2);
    KSTEP(7, yA3, yB3);

    SCORE16M(ok0, ok1, 0, 1);
  }

#undef LD
#undef KSTEP
#undef SCOREU
#undef SCOREM
#undef SCORE16U
#undef SCORE16M

  // key -> u64 (key<<32 | global index): restores unique keys for the
  // equality-pop merge. decode: mt=(k>>1)&15, ms=k&1.
#define K2E(K) ( (((unsigned long long)(K)) << 32) |                                  \
    (unsigned)(mbase + wave * 32 + lx + (((K) & 30u) >> 1) * 128 + ((K) & 1u) * 16) )

  // per-wave extraction: per query-row, 16 lanes x top-3 -> wave top-8.
  // (quads handle 4 query-rows in parallel; shfl offsets 1..8 stay in-quad)
#define EXTRACT_ROW(WIDX, T0, T1, T2) do {                                            \
    unsigned long long p0 = K2E(T0), p1 = K2E(T1), p2 = K2E(T2);                      \
    for (int rd = 0; rd < CPC; ++rd) {                                                \
      unsigned long long lm = (p0 < p1) ? p0 : p1;                                    \
      lm = (p2 < lm) ? p2 : lm;                                                       \
      unsigned long long gm = lm;                                                     \
      for (int off = 1; off < 16; off <<= 1) {                                        \
        const unsigned long long o = __shfl_xor(gm, off);                             \
        gm = (o < gm) ? o : gm;                                                       \
      }                                                                               \
      if      (p0 == gm) p0 = ~0ULL;                                                  \
      else if (p1 == gm) p1 = ~0ULL;                                                  \
      else if (p2 == gm) p2 = ~0ULL;                                                  \
      if (lx == 0) wtop[wave][WIDX][rd] = gm;                                         \
    }                                                                                 \
  } while (0)

  EXTRACT_ROW(quad * 4 + 0,      t0a, t0b, t0c);
  EXTRACT_ROW(quad * 4 + 1,      t1a, t1b, t1c);
  EXTRACT_ROW(quad * 4 + 2,      t2a, t2b, t2c);
  EXTRACT_ROW(quad * 4 + 3,      t3a, t3b, t3c);
  EXTRACT_ROW(16 + quad * 4 + 0, t4a, t4b, t4c);
  EXTRACT_ROW(16 + quad * 4 + 1, t5a, t5b, t5c);
  EXTRACT_ROW(16 + quad * 4 + 2, t6a, t6b, t6c);
  EXTRACT_ROW(16 + quad * 4 + 3, t7a, t7b, t7c);
#undef EXTRACT_ROW
#undef K2E
  __syncthreads();

  // cross-wave merge: 8 threads per query, 4 waves x 8 -> top-8 -> cand
  {
    const int qr = t >> 3;        // 0..31
    const int sp = t & 7;
    unsigned long long v0 = wtop[0][qr][sp];
    unsigned long long v1 = wtop[1][qr][sp];
    unsigned long long v2 = wtop[2][qr][sp];
    unsigned long long v3 = wtop[3][qr][sp];
    const size_t cbase = ((size_t)(q0 + qr) * NCHUNK + c) * CPC;
    for (int rd = 0; rd < CPC; ++rd) {
      unsigned long long lm = (v0 < v1) ? v0 : v1;
      const unsigned long long l2 = (v2 < v3) ? v2 : v3;
      lm = (l2 < lm) ? l2 : lm;
      unsigned long long gm = lm;
#pragma unroll
      for (int off = 1; off < 8; off <<= 1) {
        const unsigned long long o = __shfl_xor(gm, off);
        gm = (o < gm) ? o : gm;
      }
      if      (v0 == gm) v0 = ~0ULL;
      else if (v1 == gm) v1 = ~0ULL;
      else if (v2 == gm) v2 = ~0ULL;
      else if (v3 == gm) v3 = ~0ULL;
      if (sp == 0) {
        cand_s[cbase + rd] = __uint_as_float((unsigned int)(gm >> 32));
        cand_i[cbase + rd] = (int)(unsigned int)(gm & 0xffffffffu);
      }
    }
  }
}

// ---------------------------------------------------------------------------
// Finalize: per query, 256 threads (4 waves): parallel candidate merge
// 320 -> 4x16 -> top-16 (fp32 score, idx tie-break), fp64 rescore (4 cands
// per wave) -> exact top-8 order, softmax, parallel mask gather.
// ---------------------------------------------------------------------------
__global__ __launch_bounds__(256) void finalize_kernel(
    const float* __restrict__ Hq, const float* __restrict__ Hm,
    const float* __restrict__ masks,
    const float* __restrict__ cand_s, const int* __restrict__ cand_i,
    float* __restrict__ outW, float* __restrict__ outH)
{
  const int q    = blockIdx.x;
  const int t    = threadIdx.x;
  const int lane = t & 63;
  const int wave = t >> 6;

  __shared__ unsigned long long wtop[4][T16];
  __shared__ int    selIdx[T16];
  __shared__ double dArr[T16];
  __shared__ int    fin_i[KSEL];
  __shared__ double fin_d[KSEL];
  __shared__ double ew[KSEL];

  // phase 1: each wave takes 80 candidates -> its top-16 (indices unique)
  {
    const size_t base = (size_t)q * NC + (size_t)wave * (NC / 4);
    unsigned long long pk[2];
#pragma unroll
    for (int s = 0; s < 2; ++s) {
      const int c = lane + 64 * s;
      pk[s] = (c < NC / 4)
        ? ((((unsigned long long)__float_as_uint(cand_s[base + c])) << 32) | (unsigned int)cand_i[base + c])
        : ~0ULL;
    }
    for (int r = 0; r < T16; ++r) {
      unsigned long long lm = (pk[0] < pk[1]) ? pk[0] : pk[1];
      unsigned long long gm = lm;
#pragma unroll
      for (int off = 1; off < 64; off <<= 1) {
        unsigned long long o = __shfl_xor(gm, off);
        gm = (o < gm) ? o : gm;
      }
      bool done = false;
#pragma unroll
      for (int s = 0; s < 2; ++s) if (!done && pk[s] == gm) { pk[s] = ~0ULL; done = true; }
      if (lane == 0) wtop[wave][r] = gm;
    }
  }
  __syncthreads();

  // phase 2: wave 0 merges 64 -> global top-16
  if (wave == 0) {
    unsigned long long v = wtop[lane >> 4][lane & 15];
    for (int r = 0; r < T16; ++r) {
      unsigned long long gm = v;
#pragma unroll
      for (int off = 1; off < 64; off <<= 1) {
        unsigned long long o = __shfl_xor(gm, off);
        gm = (o < gm) ? o : gm;
      }
      if (v == gm) v = ~0ULL;
      if (lane == 0) selIdx[r] = (int)(unsigned int)(gm & 0xffffffffULL);
    }
  }
  __syncthreads();

  // phase 3: fp64 rescore, 4 candidates per wave
  const float4 q4 = *(const float4*)(Hq + (size_t)q * DIM + 4 * lane);
  double xp_ = (double)q4.x * q4.x + (double)q4.y * q4.y + (double)q4.z * q4.z + (double)q4.w * q4.w;
#pragma unroll
  for (int off = 1; off < 64; off <<= 1) xp_ += __shfl_xor(xp_, off);
  const double xsq = xp_;

  for (int r = wave; r < T16; r += 4) {
    const int cidx = selIdx[r];
    const float4 m4 = *(const float4*)(Hm + (size_t)cidx * DIM + 4 * lane);
    double dp = (double)q4.x * m4.x + (double)q4.y * m4.y + (double)q4.z * m4.z + (double)q4.w * m4.w;
    double yp = (double)m4.x * m4.x + (double)m4.y * m4.y + (double)m4.z * m4.z + (double)m4.w * m4.w;
#pragma unroll
    for (int off = 1; off < 64; off <<= 1) { dp += __shfl_xor(dp, off); yp += __shfl_xor(yp, off); }
    if (lane == 0) {
      double diff = xsq + yp - 2.0 * dp; if (diff < 0.0) diff = 0.0;
      double den = (1.0 - xsq) * (1.0 - yp);
      double arg = 1.0 + 2.0 * diff / (den + 1e-8);
      const double lo = 1.0 + 1e-6;
      if (arg < lo) arg = lo;
      dArr[r] = log(arg + sqrt(arg * arg - 1.0));   // arccosh
    }
  }
  __syncthreads();

  // phase 4: exact rank (dist, idx) -> top-8, softmax
  if (t < T16) {
    const double dj = dArr[t]; const int ij = selIdx[t];
    int rank = 0;
#pragma unroll
    for (int i = 0; i < T16; ++i)
      rank += (dArr[i] < dj || (dArr[i] == dj && selIdx[i] < ij)) ? 1 : 0;
    if (rank < KSEL) { fin_d[rank] = dj; fin_i[rank] = ij; }
  }
  __syncthreads();
  if (t < KSEL) ew[t] = exp(fin_d[0] - fin_d[t]);
  __syncthreads();
  if (t < KSEL) {
    double ssum = 0.0;
#pragma unroll
    for (int i = 0; i < KSEL; ++i) ssum += ew[i];
    outW[(size_t)q * KSEL + t] = (float)(ew[t] / ssum);
  }

  // phase 5: mask gather, 32 threads per output row
  const int g  = t >> 5;
  const int l0 = t & 31;
  const int row = fin_i[g];
  for (int l = l0; l < ATOMS; l += 32)
    outH[((size_t)q * KSEL + g) * ATOMS + l] = masks[(size_t)row * ATOMS + l];
}

// ---------------------------------------------------------------------------
extern "C" void kernel_launch(void* const* d_in, const int* in_sizes, int n_in,
                              void* d_out, int out_size, void* d_ws, size_t ws_size,
                              hipStream_t stream) {
  const float* Q     = (const float*)d_in[0];   // [1024,256]
  const float* M     = (const float*)d_in[1];   // [50000,256]
  const float* masks = (const float*)d_in[2];   // [50000,200]
  const float* W     = (const float*)d_in[3];   // [256,256]
  const float* bv    = (const float*)d_in[4];   // [256]
  // d_in[5] = k (always 8, hard-coded)

  char* w = (char*)d_ws;
  float*          Hq   = (float*)(w);                       //  1,048,576 B
  float*          Hm   = (float*)(w + 1048576);             // 51,200,000 B
  unsigned short* Hqb  = (unsigned short*)(w + 52248576);   //    524,288 B (frag-major, 64 groups)
  unsigned short* Hmb  = (unsigned short*)(w + 52772864);   // 25,624,576 B (frag-major, 3128 groups = 50048 rows)
  float2*         auxq = (float2*)(w + 78397440);           //      8,192 B
  float2*         auxm = (float2*)(w + 78405632);           //    400,384 B (padded to 50048)
  float*          cs   = (float*)(w + 78806016);            //  1,310,720 B
  int*            cix  = (int*)(w + 80116736);              //  1,310,720 B -> 81,427,456 total

  // Wt bf16 planes alias the cand_s region (dead until score_kernel writes it)
  unsigned short* Wt1 = (unsigned short*)(w + 78806016);    // 3 x 131,072 B
  unsigned short* Wt2 = Wt1 + DIM * DIM;
  unsigned short* Wt3 = Wt2 + DIM * DIM;

  wsplit_kernel<<<DIM, DIM, 0, stream>>>(W, Wt1, Wt2, Wt3);
  transform_kernel<<<(B_Q + TROWS - 1) / TROWS, 1024, 0, stream>>>(Q, B_Q, Wt1, Wt2, Wt3, bv, Hq, Hqb, auxq);
  transform_kernel<<<(N_M + TROWS - 1) / TROWS, 1024, 0, stream>>>(M, N_M, Wt1, Wt2, Wt3, bv, Hm, Hmb, auxm);
  score_kernel<<<dim3(NCHUNK, B_Q / 32), 256, 0, stream>>>(Hqb, Hmb, auxq, auxm, cs, cix);
  finalize_kernel<<<B_Q, 256, 0, stream>>>(Hq, Hm, masks, cs, cix,
                                           (float*)d_out, (float*)d_out + (size_t)B_Q * KSEL);
}